// Round 9
// baseline (366.988 us; speedup 1.0000x reference)
//
#include <hip/hip_runtime.h>
#include <math.h>

#define B_ 2
#define L_ 4096
#define DM 1024
#define DI 2048
#define HD 64
#define NH 32
#define DS 128
#define CH 256
#define NC 16
#define DPROJ 4384   // 2*DI + 2*DS + NH
#define CONVD 2304   // DI + 2*DS
#define NGEMM 4352   // z + xBC columns (dt handled separately)

typedef unsigned short u16;
typedef unsigned int u32;
typedef __attribute__((ext_vector_type(8))) short bf16x8;
typedef __attribute__((ext_vector_type(4))) float f32x4;

__device__ __forceinline__ float silu_(float x) { return x / (1.0f + __expf(-x)); }
__device__ __forceinline__ float us2f(u16 u) {
  union { u32 i; float f; } c; c.i = ((u32)u) << 16; return c.f;
}
__device__ __forceinline__ u16 f2us(float f) {
  union { float f; u32 i; } c; c.f = f;
  u32 i = c.i;
  return (u16)((i + 0x7FFFu + ((i >> 16) & 1u)) >> 16);  // round-nearest-even
}
__device__ __forceinline__ void unpack8(uint4 v, float* o) {
  o[0] = us2f(v.x & 0xffffu); o[1] = us2f(v.x >> 16);
  o[2] = us2f(v.y & 0xffffu); o[3] = us2f(v.y >> 16);
  o[4] = us2f(v.z & 0xffffu); o[5] = us2f(v.z >> 16);
  o[6] = us2f(v.w & 0xffffu); o[7] = us2f(v.w >> 16);
}
__device__ __forceinline__ bf16x8 scale8(bf16x8 a, float s) {
  bf16x8 r;
#pragma unroll
  for (int j = 0; j < 8; ++j) r[j] = (short)f2us(us2f((u16)a[j]) * s);
  return r;
}
__device__ __forceinline__ void gload16(const u16* g, u16* l) {
  __builtin_amdgcn_global_load_lds(
      (const __attribute__((address_space(1))) void*)g,
      (__attribute__((address_space(3))) void*)l, 16, 0, 0);
}

// ---- transpose + convert: Wt[n][k] = (bf16) W[k][n] -------------------------
__global__ __launch_bounds__(256) void cvt_t_k(const float* __restrict__ W,
                                               u16* __restrict__ Wt,
                                               int ldW, int ldT) {
  __shared__ float tile[64][65];
  const int t = threadIdx.x;
  const int n0 = blockIdx.x * 64, k0 = blockIdx.y * 64;
#pragma unroll
  for (int i = 0; i < 16; ++i) {
    int j = i * 256 + t;
    int kk = j >> 6, nn = j & 63;
    tile[kk][nn] = W[(size_t)(k0 + kk) * ldW + n0 + nn];
  }
  __syncthreads();
#pragma unroll
  for (int i = 0; i < 16; ++i) {
    int j = i * 256 + t;
    int nn = j >> 6, kk = j & 63;
    Wt[(size_t)(n0 + nn) * ldT + k0 + kk] = f2us(tile[kk][nn]);
  }
}

// ==== 256x256 multi-phase bf16 GEMM (in-proj), lag-4 counted-vmcnt ==========
// 8 waves (2M x 4N). LDS 128KB: 2 tile-buffers x (A 32KB + B 32KB).
// Gray-code phase order (mh,nh): (0,0),(0,1),(1,1),(1,0).
// Stage schedule (tile tt+1, during tile tt): q0:{A0,B0}, q1:{B1}, q2:{A1}.
// Lag table (read phase vs stage phase, in phases): A0:4/5, B0:4/7, B1:4/5,
// A1:4/5 -> min lag 4. Uniform vmcnt(8) (max 3 phases of loads outstanding)
// guarantees every half older than 3 phases has landed. Last tile drains
// {q0:4, q1:2, q2:0, q3:0}.
template <int KDIM, int NTN>
__global__ __launch_bounds__(512, 2) void gemm256_k(const u16* __restrict__ A,
                                                    const u16* __restrict__ Bt,
                                                    u16* __restrict__ zb,
                                                    u16* __restrict__ xraw,
                                                    int nwg) {
  __shared__ u16 lds[65536];
  const int t = threadIdx.x;
  const int lane = t & 63;
  const int fr = lane & 15, oct = lane >> 4;
  const int w = t >> 6;
  const int wr = w >> 2, wc = w & 3;
  const int w64base = t & ~63;
  const int q8 = nwg >> 3;
  const int wg = (blockIdx.x & 7) * q8 + (blockIdx.x >> 3);
  const int bm = wg / NTN, bn = wg % NTN;
  const int m0 = bm * 256, n0 = bn * 256;
  const int NT = KDIM >> 6;

  f32x4 acc[8][4];
#pragma unroll
  for (int i = 0; i < 8; ++i)
#pragma unroll
    for (int j = 0; j < 4; ++j) acc[i][j] = (f32x4){0.f, 0.f, 0.f, 0.f};

#define STAGE256(tt, qq)                                                        \
  {                                                                             \
    u16* dst = lds + (((tt) & 1) << 15) + (((qq) & 1) << 14) + (((qq) >> 1) << 13); \
    const u16* src = ((qq) & 1) ? Bt : A;                                       \
    const int brow = (((qq) & 1) ? n0 : m0) + (((qq) >> 1) << 7);               \
    const int k0 = (tt) << 6;                                                   \
    _Pragma("unroll")                                                           \
    for (int j_ = 0; j_ < 2; ++j_) {                                            \
      int e_ = j_ * 512 + t;                                                    \
      int r_ = e_ >> 3, s_ = e_ & 7;                                            \
      gload16(&src[(size_t)(brow + r_) * KDIM + k0 + ((s_ ^ (r_ & 7)) << 3)],   \
              &dst[(j_ * 512 + w64base) * 8]);                                  \
    }                                                                           \
  }

  // prologue: issue tile-0 halves in steady-state order A0,B0,B1,A1
  STAGE256(0, 0); STAGE256(0, 1); STAGE256(0, 3); STAGE256(0, 2);
  asm volatile("s_waitcnt vmcnt(4)" ::: "memory");  // A0,B0 landed; B1,A1 in flight
  __builtin_amdgcn_s_barrier();

  for (int tt = 0; tt < NT; ++tt) {
    const u16* Ab = lds + ((tt & 1) << 15);
    const u16* Bb = Ab + 16384;
#pragma unroll
    for (int q = 0; q < 4; ++q) {
      const int mh = q >> 1;
      const int nh = (q & 1) ^ (q >> 1);   // gray code
      bf16x8 af[4][2], bfv[2][2];
#pragma unroll
      for (int i = 0; i < 4; ++i) {
        int r = mh * 128 + wr * 64 + i * 16 + fr;
#pragma unroll
        for (int kk = 0; kk < 2; ++kk)
          af[i][kk] = *(const bf16x8*)&Ab[r * 64 + (((kk * 4 + oct) ^ (fr & 7)) << 3)];
      }
#pragma unroll
      for (int j = 0; j < 2; ++j) {
        int r = nh * 128 + wc * 32 + j * 16 + fr;
#pragma unroll
        for (int kk = 0; kk < 2; ++kk)
          bfv[j][kk] = *(const bf16x8*)&Bb[r * 64 + (((kk * 4 + oct) ^ (fr & 7)) << 3)];
      }
      if (tt + 1 < NT) {
        if (q == 0) { STAGE256(tt + 1, 0); STAGE256(tt + 1, 1); }
        else if (q == 1) { STAGE256(tt + 1, 3); }
        else if (q == 2) { STAGE256(tt + 1, 2); }
        asm volatile("s_waitcnt vmcnt(8)" ::: "memory");
      } else {
        if (q == 0)      asm volatile("s_waitcnt vmcnt(4)" ::: "memory");
        else if (q == 1) asm volatile("s_waitcnt vmcnt(2)" ::: "memory");
        else             asm volatile("s_waitcnt vmcnt(0)" ::: "memory");
      }
      __builtin_amdgcn_s_barrier();
      __builtin_amdgcn_s_setprio(1);
#pragma unroll
      for (int kk = 0; kk < 2; ++kk)
#pragma unroll
        for (int i = 0; i < 4; ++i)
#pragma unroll
          for (int j = 0; j < 2; ++j)
            acc[mh * 4 + i][nh * 2 + j] = __builtin_amdgcn_mfma_f32_16x16x32_bf16(
                af[i][kk], bfv[j][kk], acc[mh * 4 + i][nh * 2 + j], 0, 0, 0);
      __builtin_amdgcn_s_setprio(0);
      __builtin_amdgcn_s_barrier();
    }
  }
#undef STAGE256

  // coalesced epilogue: 4 passes of 64 rows via LDS
  const bool isz = (n0 < DI);
  u16* Oh = lds;  // [64][264]
#pragma unroll
  for (int P = 0; P < 4; ++P) {
    __syncthreads();
    if (wr == (P & 1)) {
      const int mhP = P >> 1;
#pragma unroll
      for (int i = 0; i < 4; ++i) {
        int mf = mhP * 4 + i;
        int rbase = i * 16 + oct * 4;
#pragma unroll
        for (int ri = 0; ri < 4; ++ri)
#pragma unroll
          for (int nf = 0; nf < 4; ++nf) {
            int cloc = (nf >> 1) * 128 + wc * 32 + (nf & 1) * 16 + fr;
            Oh[(rbase + ri) * 264 + cloc] = f2us(acc[mf][nf][ri]);
          }
      }
    }
    __syncthreads();
#pragma unroll
    for (int p = 0; p < 4; ++p) {
      int e = p * 512 + t;
      int row = e >> 5, cs = (e & 31) * 8;
      uint4 v = *(const uint4*)&Oh[row * 264 + cs];
      size_t grow = m0 + P * 64 + row;
      int col = n0 + cs;
      if (isz) *(uint4*)&zb[grow * DI + col] = v;
      else     *(uint4*)&xraw[grow * CONVD + (col - DI)] = v;
    }
  }
}

// ---- bf16 MFMA GEMM 128x128 (out-proj, EPI1 fp32 out) -----------------------
template <int KDIM, int NTN, int EPI>
__global__ __launch_bounds__(256) void gemm_bf16_k(const u16* __restrict__ A,
                                                   const u16* __restrict__ Bt,
                                                   u16* __restrict__ zb,
                                                   u16* __restrict__ xraw,
                                                   float* __restrict__ outf,
                                                   int nwg) {
  __shared__ u16 pool[(EPI == 1) ? 17408 : 16384];
  u16* Al = pool;
  u16* Bl = pool + 8192;
  const int t = threadIdx.x;
  const int wv = t >> 6, lane = t & 63;
  const int fr = lane & 15, oct = lane >> 4;
  const int wr = wv >> 1, wc = wv & 1;
  const int q = nwg >> 3;
  const int wg = (blockIdx.x & 7) * q + (blockIdx.x >> 3);
  const int bm = wg / NTN, bn = wg % NTN;
  const int m0 = bm * 128, n0 = bn * 128;

  const int lr = lane >> 3, ls = lane & 7;
  const int gslot = (ls ^ lr) * 8;

  f32x4 acc[4][4];
#pragma unroll
  for (int mm = 0; mm < 4; ++mm)
#pragma unroll
    for (int nn = 0; nn < 4; ++nn) acc[mm][nn] = (f32x4){0.f, 0.f, 0.f, 0.f};

  for (int k0 = 0; k0 < KDIM; k0 += 64) {
    if (k0) __syncthreads();
#pragma unroll
    for (int i = 0; i < 4; ++i) {
      const int rowA = wv * 32 + i * 8;
      gload16(&A[(size_t)(m0 + rowA + lr) * KDIM + k0 + gslot], &Al[rowA * 64]);
      gload16(&Bt[(size_t)(n0 + rowA + lr) * KDIM + k0 + gslot], &Bl[rowA * 64]);
    }
    __syncthreads();
#pragma unroll
    for (int kk = 0; kk < 2; ++kk) {
      bf16x8 af[4], bfr[4];
#pragma unroll
      for (int mm = 0; mm < 4; ++mm)
        af[mm] = *(const bf16x8*)&Al[(wr * 64 + mm * 16 + fr) * 64 +
                                     (((kk * 4 + oct) ^ (fr & 7)) * 8)];
#pragma unroll
      for (int nn = 0; nn < 4; ++nn)
        bfr[nn] = *(const bf16x8*)&Bl[(wc * 64 + nn * 16 + fr) * 64 +
                                      (((kk * 4 + oct) ^ (fr & 7)) * 8)];
#pragma unroll
      for (int mm = 0; mm < 4; ++mm)
#pragma unroll
        for (int nn = 0; nn < 4; ++nn)
          acc[mm][nn] = __builtin_amdgcn_mfma_f32_16x16x32_bf16(af[mm], bfr[nn],
                                                                acc[mm][nn], 0, 0, 0);
    }
  }

  if (EPI == 0) {
    const bool isz = (n0 < DI);
#pragma unroll
    for (int P = 0; P < 2; ++P) {
      __syncthreads();
      u16* Oh = pool;
      if (wr == P) {
#pragma unroll
        for (int mm = 0; mm < 4; ++mm)
#pragma unroll
          for (int i = 0; i < 4; ++i) {
            int rloc = mm * 16 + oct * 4 + i;
#pragma unroll
            for (int nn = 0; nn < 4; ++nn)
              Oh[rloc * 136 + wc * 64 + nn * 16 + fr] = f2us(acc[mm][nn][i]);
          }
      }
      __syncthreads();
#pragma unroll
      for (int p = 0; p < 4; ++p) {
        int e = p * 256 + t;
        int row = e >> 4, cs = (e & 15) * 8;
        uint4 v = *(const uint4*)&Oh[row * 136 + cs];
        size_t grow = m0 + P * 64 + row;
        int col = n0 + cs;
        if (isz) *(uint4*)&zb[grow * DI + col] = v;
        else     *(uint4*)&xraw[grow * CONVD + (col - DI)] = v;
      }
    }
  } else {
#pragma unroll
    for (int P = 0; P < 2; ++P) {
      __syncthreads();
      float* Of = (float*)pool;
      if (wr == P) {
#pragma unroll
        for (int mm = 0; mm < 4; ++mm)
#pragma unroll
          for (int i = 0; i < 4; ++i) {
            int rloc = mm * 16 + oct * 4 + i;
#pragma unroll
            for (int nn = 0; nn < 4; ++nn)
              Of[rloc * 132 + wc * 64 + nn * 16 + fr] = acc[mm][nn][i];
          }
      }
      __syncthreads();
#pragma unroll
      for (int p = 0; p < 8; ++p) {
        int e = p * 256 + t;
        int row = e >> 5, c4 = (e & 31) * 4;
        float4 v = *(const float4*)&Of[row * 132 + c4];
        *(float4*)&outf[(size_t)(m0 + P * 64 + row) * DM + n0 + c4] = v;
      }
    }
  }
}

// ---- dt (fp32 exact) + x->bf16 fused ----------------------------------------
__global__ __launch_bounds__(256) void dt_gemm_k(const float* __restrict__ x,
                                                 const float* __restrict__ W,
                                                 const float* __restrict__ dtb,
                                                 float* __restrict__ dtp,
                                                 u16* __restrict__ xb16) {
  __shared__ float xs[8 * 1024];
  const int t = threadIdx.x;
  const int row0 = blockIdx.x * 8;
#pragma unroll
  for (int i = 0; i < 8; ++i) {
    int j4 = i * 256 + t;
    float4 v = *(const float4*)&x[(size_t)row0 * DM + j4 * 4];
    *(float4*)&xs[j4 * 4] = v;
    u32 lo = (u32)f2us(v.x) | ((u32)f2us(v.y) << 16);
    u32 hi = (u32)f2us(v.z) | ((u32)f2us(v.w) << 16);
    *(uint2*)&xb16[(size_t)row0 * DM + j4 * 4] = make_uint2(lo, hi);
  }
  __syncthreads();
  const int r = t >> 5, h = t & 31;
  float a0 = 0.f, a1 = 0.f, a2 = 0.f, a3 = 0.f;
  const float* wcol = W + (DI + CONVD) + h;
  const float* xr = &xs[r * 1024];
  for (int k = 0; k < 1024; k += 4) {
    float4 xv = *(const float4*)&xr[k];
    a0 += xv.x * wcol[(size_t)(k + 0) * DPROJ];
    a1 += xv.y * wcol[(size_t)(k + 1) * DPROJ];
    a2 += xv.z * wcol[(size_t)(k + 2) * DPROJ];
    a3 += xv.w * wcol[(size_t)(k + 3) * DPROJ];
  }
  float v = (a0 + a1) + (a2 + a3) + dtb[h];
  dtp[(size_t)(row0 + r) * NH + h] = (v > 20.0f) ? v : log1pf(__expf(v));
}

// ---- causal depthwise conv(4) + SiLU ----------------------------------------
__global__ __launch_bounds__(256) void conv_silu_k(const u16* __restrict__ xraw,
                                                   const float* __restrict__ cw,
                                                   const float* __restrict__ cb,
                                                   u16* __restrict__ xbc) {
  int idx = blockIdx.x * 256 + threadIdx.x;
  int ch8 = idx % (CONVD / 8);
  int bl = idx / (CONVD / 8);
  int l = bl & (L_ - 1);
  int ch = ch8 * 8;
  const u16* src = xraw + (size_t)bl * CONVD + ch;
  float a[8], o[8];
#pragma unroll
  for (int qq = 0; qq < 8; ++qq) a[qq] = cb[ch + qq];
  float w0[8], w1[8], w2[8], w3[8];
#pragma unroll
  for (int qq = 0; qq < 8; ++qq) {
    float4 w = *(const float4*)&cw[(ch + qq) * 4];
    w0[qq] = w.x; w1[qq] = w.y; w2[qq] = w.z; w3[qq] = w.w;
  }
  if (l >= 3) {
    uint4 v = *(const uint4*)&src[-3 * CONVD]; unpack8(v, o);
#pragma unroll
    for (int qq = 0; qq < 8; ++qq) a[qq] += o[qq] * w0[qq];
  }
  if (l >= 2) {
    uint4 v = *(const uint4*)&src[-2 * CONVD]; unpack8(v, o);
#pragma unroll
    for (int qq = 0; qq < 8; ++qq) a[qq] += o[qq] * w1[qq];
  }
  if (l >= 1) {
    uint4 v = *(const uint4*)&src[-CONVD]; unpack8(v, o);
#pragma unroll
    for (int qq = 0; qq < 8; ++qq) a[qq] += o[qq] * w2[qq];
  }
  {
    uint4 v = *(const uint4*)&src[0]; unpack8(v, o);
#pragma unroll
    for (int qq = 0; qq < 8; ++qq) a[qq] += o[qq] * w3[qq];
  }
  uint4 ov;
  ov.x = (u32)f2us(silu_(a[0])) | ((u32)f2us(silu_(a[1])) << 16);
  ov.y = (u32)f2us(silu_(a[2])) | ((u32)f2us(silu_(a[3])) << 16);
  ov.z = (u32)f2us(silu_(a[4])) | ((u32)f2us(silu_(a[5])) << 16);
  ov.w = (u32)f2us(silu_(a[6])) | ((u32)f2us(silu_(a[7])) << 16);
  *(uint4*)&xbc[(size_t)bl * CONVD + ch] = ov;
}

// ---- per-(b,h,c) cumsum of dt*A ---------------------------------------------
__global__ __launch_bounds__(256) void acs_k(const float* __restrict__ dtp,
                                             const float* __restrict__ A_log,
                                             float* __restrict__ Acs) {
  const int t = threadIdx.x;
  const int lane = t & 63, wv = t >> 6;
  const int idx = blockIdx.x * 4 + wv;
  const int h = (idx >> 4) & (NH - 1);
  const int c = idx & (NC - 1);
  const int b = idx >> 9;
  const float Ah = -__expf(A_log[h]);
  const size_t base = ((size_t)b * L_ + c * CH + lane * 4) * NH + h;
  float v0 = dtp[base] * Ah;
  float v1 = dtp[base + NH] * Ah;
  float v2 = dtp[base + 2 * NH] * Ah;
  float v3 = dtp[base + 3 * NH] * Ah;
  float c1 = v0 + v1, c2 = c1 + v2, c3 = c2 + v3;
  float tot = c3;
#pragma unroll
  for (int off = 1; off < 64; off <<= 1) {
    float p = __shfl_up(tot, off, 64);
    if (lane >= off) tot += p;
  }
  float excl = tot - c3;
  float4 ov = make_float4(excl + v0, excl + c1, excl + c2, excl + c3);
  *(float4*)&Acs[(size_t)idx * CH + lane * 4] = ov;
}

// ---- chunk end-states via MFMA -> bf16 --------------------------------------
#define SLP 72
__global__ __launch_bounds__(256) void states_k(const u16* __restrict__ xbc,
                                                const float* __restrict__ dtp,
                                                const float* __restrict__ Acs,
                                                u16* __restrict__ st16) {
  __shared__ u16 BtT[128 * SLP];
  __shared__ u16 XtT[64 * SLP];
  const int t = threadIdx.x;
  const int wv = t >> 6, lane = t & 63;
  const int fr = lane & 15, oct = lane >> 4;
  const int h = blockIdx.x & 31, c = (blockIdx.x >> 5) & 15, b = blockIdx.x >> 9;
  const size_t acsb = (((size_t)b * NH + h) * NC + c) * CH;
  const float acs_last = Acs[acsb + (CH - 1)];
  const size_t rowbase = (size_t)b * L_ + c * CH;

  f32x4 acc[2][4];
#pragma unroll
  for (int mt = 0; mt < 2; ++mt)
#pragma unroll
    for (int pt = 0; pt < 4; ++pt) acc[mt][pt] = (f32x4){0.f, 0.f, 0.f, 0.f};

  for (int lt = 0; lt < 4; ++lt) {
    __syncthreads();
#pragma unroll
    for (int i = 0; i < 4; ++i) {
      int ci = i * 256 + t;
      int l = ci >> 4, nk = ci & 15;
      uint4 v = *(const uint4*)&xbc[(rowbase + lt * 64 + l) * CONVD + DI + nk * 8];
      u16 p8[8];
      p8[0] = (u16)(v.x & 0xffffu); p8[1] = (u16)(v.x >> 16);
      p8[2] = (u16)(v.y & 0xffffu); p8[3] = (u16)(v.y >> 16);
      p8[4] = (u16)(v.z & 0xffffu); p8[5] = (u16)(v.z >> 16);
      p8[6] = (u16)(v.w & 0xffffu); p8[7] = (u16)(v.w >> 16);
#pragma unroll
      for (int qq = 0; qq < 8; ++qq) {
        int r = nk * 8 + qq;
        BtT[r * SLP + ((((l >> 3) ^ (r >> 3)) & 7) << 3) + (l & 7)] = p8[qq];
      }
    }
#pragma unroll
    for (int i = 0; i < 2; ++i) {
      int ci = i * 256 + t;
      int l = ci >> 3, pk = ci & 7;
      size_t row = rowbase + lt * 64 + l;
      uint4 v = *(const uint4*)&xbc[row * CONVD + h * HD + pk * 8];
      float d = dtp[row * NH + h] * __expf(acs_last - Acs[acsb + lt * 64 + l]);
      float o[8]; unpack8(v, o);
#pragma unroll
      for (int qq = 0; qq < 8; ++qq) {
        int r = pk * 8 + qq;
        XtT[r * SLP + ((((l >> 3) ^ (r >> 3)) & 7) << 3) + (l & 7)] = f2us(o[qq] * d);
      }
    }
    __syncthreads();
#pragma unroll
    for (int ks = 0; ks < 2; ++ks) {
      bf16x8 afr[2], bfr[4];
#pragma unroll
      for (int mt = 0; mt < 2; ++mt) {
        int r = wv * 32 + mt * 16 + fr;
        afr[mt] = *(const bf16x8*)&BtT[r * SLP + ((((ks * 4 + oct) ^ (r >> 3)) & 7) << 3)];
      }
#pragma unroll
      for (int pt = 0; pt < 4; ++pt) {
        int r = pt * 16 + fr;
        bfr[pt] = *(const bf16x8*)&XtT[r * SLP + ((((ks * 4 + oct) ^ (r >> 3)) & 7) << 3)];
      }
#pragma unroll
      for (int mt = 0; mt < 2; ++mt)
#pragma unroll
        for (int pt = 0; pt < 4; ++pt)
          acc[mt][pt] = __builtin_amdgcn_mfma_f32_16x16x32_bf16(afr[mt], bfr[pt],
                                                                acc[mt][pt], 0, 0, 0);
    }
  }
  size_t sbase = (((size_t)b * NC + c) * NH + h) * (size_t)(HD * DS);
#pragma unroll
  for (int mt = 0; mt < 2; ++mt)
#pragma unroll
    for (int pt = 0; pt < 4; ++pt) {
      int p = pt * 16 + fr;
      int n0 = wv * 32 + mt * 16 + oct * 4;
      u32 lo = (u32)f2us(acc[mt][pt][0]) | ((u32)f2us(acc[mt][pt][1]) << 16);
      u32 hi = (u32)f2us(acc[mt][pt][2]) | ((u32)f2us(acc[mt][pt][3]) << 16);
      *(uint2*)&st16[sbase + (size_t)p * DS + n0] = make_uint2(lo, hi);
    }
}

// ---- inter-chunk scan (bf16 states, fp32 carry) -----------------------------
__global__ __launch_bounds__(256) void scan_k(u16* __restrict__ st16,
                                              const float* __restrict__ Acs) {
  const int t = threadIdx.x;
  const int seg = blockIdx.x & 15;
  const int bh = blockIdx.x >> 4;
  const int h = bh & 31, b = bh >> 5;
  const int e2 = seg * 256 + t;
  const size_t acssb = ((size_t)b * NH + h) * NC * CH;
  float run0 = 0.0f, run1 = 0.0f;
#pragma unroll
  for (int c = 0; c < NC; ++c) {
    float dAl = __expf(Acs[acssb + (size_t)c * CH + (CH - 1)]);
    size_t e = (((size_t)b * NC + c) * NH + h) * (size_t)(HD * DS) + e2 * 2;
    u32 v = *(const u32*)&st16[e];
    float s0 = us2f((u16)(v & 0xffffu)), s1 = us2f((u16)(v >> 16));
    *(u32*)&st16[e] = (u32)f2us(run0) | ((u32)f2us(run1) << 16);
    run0 = fmaf(dAl, run0, s0);
    run1 = fmaf(dAl, run1, s1);
  }
}

// ---- merged SSD: one 8-wave block per (b,c,h) -------------------------------
#define SP 72
#define XOFF 8192
#define POFF 12800
__global__ __launch_bounds__(512, 4) void ssd_out_k(const u16* __restrict__ xbc,
                                                    const float* __restrict__ dtp,
                                                    const float* __restrict__ Acs,
                                                    const u16* __restrict__ st16,
                                                    const float* __restrict__ Dvec,
                                                    u16* __restrict__ y) {
  __shared__ u16 pool[31232];
  __shared__ float acs_s[256];
  const int t = threadIdx.x;
  const int w = t >> 6, lane = t & 63;
  const int fr = lane & 15, oct = lane >> 4;
  const int h = blockIdx.x & 31, c = (blockIdx.x >> 5) & 15, b = blockIdx.x >> 9;
  const size_t acsb = (((size_t)b * NH + h) * NC + c) * CH;
  const size_t rowbase = (size_t)b * L_ + c * CH;
  if (t < 256) acs_s[t] = Acs[acsb + t];
  const size_t sb = (((size_t)b * NC + c) * NH + h) * (size_t)(HD * DS);
#pragma unroll
  for (int i = 0; i < 2; ++i) {
    int ci = i * 512 + t; int p = ci >> 4, nk = ci & 15;
    uint4 v = *(const uint4*)&st16[sb + (size_t)p * DS + nk * 8];
    *(uint4*)&pool[p * 136 + nk * 8] = v;
  }
  __syncthreads();
  bf16x8 ca[2][4];
#pragma unroll
  for (int mt = 0; mt < 2; ++mt)
#pragma unroll
    for (int kk = 0; kk < 4; ++kk)
      ca[mt][kk] = *(const bf16x8*)&xbc[(rowbase + w * 32 + mt * 16 + fr) * CONVD +
                                        DI + DS + kk * 32 + oct * 8];
  f32x4 acc_y[2][4];
#pragma unroll
  for (int mt = 0; mt < 2; ++mt)
#pragma unroll
    for (int pp4 = 0; pp4 < 4; ++pp4) acc_y[mt][pp4] = (f32x4){0.f, 0.f, 0.f, 0.f};

  {
    float eL0 = __expf(acs_s[w * 32 + fr]);
    float eL1 = __expf(acs_s[w * 32 + 16 + fr]);
#pragma unroll
    for (int kk = 0; kk < 4; ++kk) {
      bf16x8 c0 = scale8(ca[0][kk], eL0);
      bf16x8 c1 = scale8(ca[1][kk], eL1);
#pragma unroll
      for (int pp4 = 0; pp4 < 4; ++pp4) {
        bf16x8 sf = *(const bf16x8*)&pool[(pp4 * 16 + fr) * 136 + kk * 32 + oct * 8];
        acc_y[0][pp4] = __builtin_amdgcn_mfma_f32_16x16x32_bf16(c0, sf, acc_y[0][pp4], 0, 0, 0);
        acc_y[1][pp4] = __builtin_amdgcn_mfma_f32_16x16x32_bf16(c1, sf, acc_y[1][pp4], 0, 0, 0);
      }
    }
  }

  const int stmax = w >> 1, delta = (w & 1) << 5;
  for (int st = 0; st < 4; ++st) {
    __syncthreads();
#pragma unroll
    for (int i = 0; i < 2; ++i) {
      int ci = i * 512 + t; int ll = ci >> 4, ck = ci & 15;
      uint4 v = *(const uint4*)&xbc[(rowbase + st * 64 + ll) * CONVD + DI + ck * 8];
      *(uint4*)&pool[ll * 128 + ((ck * 8) ^ ((ll & 7) << 3))] = v;
    }
    {
      int s = t >> 3, pk = t & 7;
      size_t row = rowbase + st * 64 + s;
      uint4 v = *(const uint4*)&xbc[row * CONVD + h * HD + pk * 8];
      float d = dtp[row * NH + h];
      float o[8]; unpack8(v, o);
#pragma unroll
      for (int qq = 0; qq < 8; ++qq) {
        int r = pk * 8 + qq;
        pool[XOFF + r * SP + ((((s >> 3) ^ (r >> 3)) & 7) << 3) + (s & 7)] = f2us(o[qq] * d);
      }
    }
    __syncthreads();
    if (st > stmax) continue;
    const bool diag = (st == stmax);
#pragma unroll
    for (int ss4 = 0; ss4 < 4; ++ss4) {
      bf16x8 bbf[4];
#pragma unroll
      for (int kk = 0; kk < 4; ++kk)
        bbf[kk] = *(const bf16x8*)&pool[(ss4 * 16 + fr) * 128 +
                                        ((kk * 32 + oct * 8) ^ ((fr & 7) << 3))];
      int s_in = ss4 * 16 + fr;
      float aS = acs_s[st * 64 + s_in];
#pragma unroll
      for (int mt = 0; mt < 2; ++mt) {
        f32x4 sacc = (f32x4){0.f, 0.f, 0.f, 0.f};
#pragma unroll
        for (int kk = 0; kk < 4; ++kk)
          sacc = __builtin_amdgcn_mfma_f32_16x16x32_bf16(ca[mt][kk], bbf[kk], sacc, 0, 0, 0);
#pragma unroll
        for (int i = 0; i < 4; ++i) {
          int r = mt * 16 + oct * 4 + i;
          float aL = acs_s[w * 32 + r];
          float wgt = (!diag || (s_in <= r + delta)) ? __expf(aL - aS) : 0.0f;
          pool[POFF + w * 2304 + r * SP + s_in] = f2us(sacc[i] * wgt);
        }
      }
    }
    bf16x8 pa[2][2];
#pragma unroll
    for (int mt = 0; mt < 2; ++mt)
#pragma unroll
      for (int k2 = 0; k2 < 2; ++k2)
        pa[mt][k2] = *(const bf16x8*)&pool[POFF + w * 2304 + (mt * 16 + fr) * SP +
                                           k2 * 32 + oct * 8];
#pragma unroll
    for (int pp4 = 0; pp4 < 4; ++pp4) {
      int rx = pp4 * 16 + fr, xg = rx >> 3;
      bf16x8 xb0 = *(const bf16x8*)&pool[XOFF + rx * SP + (((oct) ^ xg) & 7) * 8];
      bf16x8 xb1 = *(const bf16x8*)&pool[XOFF + rx * SP + (((4 + oct) ^ xg) & 7) * 8];
#pragma unroll
      for (int mt = 0; mt < 2; ++mt) {
        acc_y[mt][pp4] = __builtin_amdgcn_mfma_f32_16x16x32_bf16(pa[mt][0], xb0, acc_y[mt][pp4], 0, 0, 0);
        acc_y[mt][pp4] = __builtin_amdgcn_mfma_f32_16x16x32_bf16(pa[mt][1], xb1, acc_y[mt][pp4], 0, 0, 0);
      }
    }
  }

  const float Dh = Dvec[h];
#pragma unroll
  for (int mt = 0; mt < 2; ++mt)
#pragma unroll
    for (int i = 0; i < 4; ++i) {
      size_t row = rowbase + w * 32 + mt * 16 + oct * 4 + i;
#pragma unroll
      for (int pp4 = 0; pp4 < 4; ++pp4) {
        int col = h * HD + pp4 * 16 + fr;
        float xs = us2f(xbc[row * CONVD + col]);
        y[row * DI + col] = f2us(acc_y[mt][pp4][i] + Dh * xs);
      }
    }
}

// ---- gated RMSNorm in place on y (bf16) -------------------------------------
__global__ __launch_bounds__(256) void gnorm_k(const u16* __restrict__ zb,
                                               const float* __restrict__ nw,
                                               u16* __restrict__ y) {
  const int row = blockIdx.x, t = threadIdx.x;
  const u16* zr = zb + (size_t)row * DI;
  u16* yr = y + (size_t)row * DI;
  uint4 zv = *(const uint4*)&zr[t * 8];
  uint4 yv = *(const uint4*)&yr[t * 8];
  float uz[8], uy[8];
  unpack8(zv, uz); unpack8(yv, uy);
  float u[8], ssum = 0.0f;
#pragma unroll
  for (int j = 0; j < 8; ++j) { u[j] = uy[j] * silu_(uz[j]); ssum += u[j] * u[j]; }
#pragma unroll
  for (int off = 32; off >= 1; off >>= 1) ssum += __shfl_xor(ssum, off, 64);
  __shared__ float red[4];
  if ((t & 63) == 0) red[t >> 6] = ssum;
  __syncthreads();
  float sc = rsqrtf((red[0] + red[1] + red[2] + red[3]) * (1.0f / DI) + 1e-5f);
  float4 w0 = *(const float4*)&nw[t * 8];
  float4 w1 = *(const float4*)&nw[t * 8 + 4];
  float o0 = u[0] * sc * w0.x, o1 = u[1] * sc * w0.y, o2 = u[2] * sc * w0.z, o3 = u[3] * sc * w0.w;
  float o4 = u[4] * sc * w1.x, o5 = u[5] * sc * w1.y, o6 = u[6] * sc * w1.z, o7 = u[7] * sc * w1.w;
  uint4 ov;
  ov.x = (u32)f2us(o0) | ((u32)f2us(o1) << 16);
  ov.y = (u32)f2us(o2) | ((u32)f2us(o3) << 16);
  ov.z = (u32)f2us(o4) | ((u32)f2us(o5) << 16);
  ov.w = (u32)f2us(o6) | ((u32)f2us(o7) << 16);
  *(uint4*)&yr[t * 8] = ov;
}

extern "C" void kernel_launch(void* const* d_in, const int* in_sizes, int n_in,
                              void* d_out, int out_size, void* d_ws, size_t ws_size,
                              hipStream_t stream) {
  const float* x      = (const float*)d_in[0];
  const float* W_in   = (const float*)d_in[1];
  const float* conv_w = (const float*)d_in[2];
  const float* conv_b = (const float*)d_in[3];
  const float* dt_b   = (const float*)d_in[4];
  const float* A_log  = (const float*)d_in[5];
  const float* Dvec   = (const float*)d_in[6];
  const float* norm_w = (const float*)d_in[7];
  const float* W_out  = (const float*)d_in[8];
  float* out = (float*)d_out;

  u16* zb       = (u16*)d_ws;                              // 33.55 MB
  u16* xbc      = zb + (size_t)B_ * L_ * DI;               // 37.75 MB
  float* dtp    = (float*)(xbc + (size_t)B_ * L_ * CONVD); // 1.05 MB
  float* Acs    = dtp + (size_t)B_ * L_ * NH;              // 1.05 MB
  u16* stregion = (u16*)(Acs + (size_t)B_ * NH * L_);      // 33.55 MB region
  u16* uni      = stregion + (size_t)B_ * NC * NH * HD * DS * 2;  // 37.75 MB
  u16* xraw = uni;
  u16* y    = uni;

  u16* xb16     = stregion;
  u16* wint     = stregion + (size_t)B_ * L_ * DM;
  u16* states16 = stregion;
  u16* woutt    = stregion;

  const int Mrows = B_ * L_;

  dt_gemm_k<<<Mrows / 8, 256, 0, stream>>>(x, W_in, dt_b, dtp, xb16);
  cvt_t_k<<<dim3(NGEMM / 64, DM / 64), 256, 0, stream>>>(W_in, wint, DPROJ, DM);

  const int nwg_in = (Mrows / 256) * (NGEMM / 256);   // 32*17 = 544
  gemm256_k<DM, NGEMM / 256><<<nwg_in, 512, 0, stream>>>(xb16, wint, zb, xraw, nwg_in);

  conv_silu_k<<<(Mrows * (CONVD / 8)) / 256, 256, 0, stream>>>(xraw, conv_w, conv_b, xbc);
  acs_k<<<(B_ * NH * NC) / 4, 256, 0, stream>>>(dtp, A_log, Acs);
  states_k<<<B_ * NC * NH, 256, 0, stream>>>(xbc, dtp, Acs, states16);
  scan_k<<<B_ * NH * 16, 256, 0, stream>>>(states16, Acs);
  ssd_out_k<<<B_ * NC * NH, 512, 0, stream>>>(xbc, dtp, Acs, states16, Dvec, y);
  gnorm_k<<<Mrows, 256, 0, stream>>>(zb, norm_w, y);

  cvt_t_k<<<dim3(DM / 64, DI / 64), 256, 0, stream>>>(W_out, woutt, DM, DI);
  const int nwg_out = (Mrows / 128) * (DM / 128);     // 512
  gemm_bf16_k<DI, DM / 128, 1><<<nwg_out, 256, 0, stream>>>(
      y, woutt, nullptr, nullptr, out, nwg_out);
}

// Round 10
// 348.065 us; speedup vs baseline: 1.0544x; 1.0544x over previous
//
#include <hip/hip_runtime.h>
#include <math.h>

#define B_ 2
#define L_ 4096
#define DM 1024
#define DI 2048
#define HD 64
#define NH 32
#define DS 128
#define CH 256
#define NC 16
#define DPROJ 4384   // 2*DI + 2*DS + NH
#define CONVD 2304   // DI + 2*DS
#define NGEMM 4352   // z + xBC columns (dt handled separately)

typedef unsigned short u16;
typedef unsigned int u32;
typedef __attribute__((ext_vector_type(8))) short bf16x8;
typedef __attribute__((ext_vector_type(4))) float f32x4;

__device__ __forceinline__ float silu_(float x) { return x / (1.0f + __expf(-x)); }
__device__ __forceinline__ float us2f(u16 u) {
  union { u32 i; float f; } c; c.i = ((u32)u) << 16; return c.f;
}
__device__ __forceinline__ u16 f2us(float f) {
  union { float f; u32 i; } c; c.f = f;
  u32 i = c.i;
  return (u16)((i + 0x7FFFu + ((i >> 16) & 1u)) >> 16);  // round-nearest-even
}
__device__ __forceinline__ void unpack8(uint4 v, float* o) {
  o[0] = us2f(v.x & 0xffffu); o[1] = us2f(v.x >> 16);
  o[2] = us2f(v.y & 0xffffu); o[3] = us2f(v.y >> 16);
  o[4] = us2f(v.z & 0xffffu); o[5] = us2f(v.z >> 16);
  o[6] = us2f(v.w & 0xffffu); o[7] = us2f(v.w >> 16);
}
__device__ __forceinline__ bf16x8 scale8(bf16x8 a, float s) {
  bf16x8 r;
#pragma unroll
  for (int j = 0; j < 8; ++j) r[j] = (short)f2us(us2f((u16)a[j]) * s);
  return r;
}
__device__ __forceinline__ void gload16(const u16* g, u16* l) {
  __builtin_amdgcn_global_load_lds(
      (const __attribute__((address_space(1))) void*)g,
      (__attribute__((address_space(3))) void*)l, 16, 0, 0);
}

// ---- transpose + convert: Wt[n][k] = (bf16) W[k][n] -------------------------
__global__ __launch_bounds__(256) void cvt_t_k(const float* __restrict__ W,
                                               u16* __restrict__ Wt,
                                               int ldW, int ldT) {
  __shared__ float tile[64][65];
  const int t = threadIdx.x;
  const int n0 = blockIdx.x * 64, k0 = blockIdx.y * 64;
#pragma unroll
  for (int i = 0; i < 16; ++i) {
    int j = i * 256 + t;
    int kk = j >> 6, nn = j & 63;
    tile[kk][nn] = W[(size_t)(k0 + kk) * ldW + n0 + nn];
  }
  __syncthreads();
#pragma unroll
  for (int i = 0; i < 16; ++i) {
    int j = i * 256 + t;
    int nn = j >> 6, kk = j & 63;
    Wt[(size_t)(n0 + nn) * ldT + k0 + kk] = f2us(tile[kk][nn]);
  }
}

// ---- bf16 MFMA GEMM: D = A(MxK) . Bt(NxK)^T, 128x128 tile, BK=64 -----------
// m97 structure: global_load_lds(16B), single LDS buffer, 2 barriers/K-step.
// EPI 0: split bf16 into zb / xraw.   EPI 1: fp32 out (N = DM).
template <int KDIM, int NTN, int EPI>
__global__ __launch_bounds__(256) void gemm_bf16_k(const u16* __restrict__ A,
                                                   const u16* __restrict__ Bt,
                                                   u16* __restrict__ zb,
                                                   u16* __restrict__ xraw,
                                                   float* __restrict__ outf,
                                                   int nwg) {
  __shared__ u16 pool[(EPI == 1) ? 17408 : 16384];
  u16* Al = pool;
  u16* Bl = pool + 8192;
  const int t = threadIdx.x;
  const int wv = t >> 6, lane = t & 63;
  const int fr = lane & 15, oct = lane >> 4;
  const int wr = wv >> 1, wc = wv & 1;
  const int q = nwg >> 3;
  const int wg = (blockIdx.x & 7) * q + (blockIdx.x >> 3);
  const int bm = wg / NTN, bn = wg % NTN;
  const int m0 = bm * 128, n0 = bn * 128;

  const int lr = lane >> 3, ls = lane & 7;
  const int gslot = (ls ^ lr) * 8;   // XOR involution: LDS[r][s] = G[r][s^(r&7)]

  f32x4 acc[4][4];
#pragma unroll
  for (int mm = 0; mm < 4; ++mm)
#pragma unroll
    for (int nn = 0; nn < 4; ++nn) acc[mm][nn] = (f32x4){0.f, 0.f, 0.f, 0.f};

  for (int k0 = 0; k0 < KDIM; k0 += 64) {
    if (k0) __syncthreads();
#pragma unroll
    for (int i = 0; i < 4; ++i) {
      const int rowA = wv * 32 + i * 8;
      gload16(&A[(size_t)(m0 + rowA + lr) * KDIM + k0 + gslot], &Al[rowA * 64]);
      gload16(&Bt[(size_t)(n0 + rowA + lr) * KDIM + k0 + gslot], &Bl[rowA * 64]);
    }
    __syncthreads();
#pragma unroll
    for (int kk = 0; kk < 2; ++kk) {
      bf16x8 af[4], bfr[4];
#pragma unroll
      for (int mm = 0; mm < 4; ++mm)
        af[mm] = *(const bf16x8*)&Al[(wr * 64 + mm * 16 + fr) * 64 +
                                     (((kk * 4 + oct) ^ (fr & 7)) * 8)];
#pragma unroll
      for (int nn = 0; nn < 4; ++nn)
        bfr[nn] = *(const bf16x8*)&Bl[(wc * 64 + nn * 16 + fr) * 64 +
                                      (((kk * 4 + oct) ^ (fr & 7)) * 8)];
#pragma unroll
      for (int mm = 0; mm < 4; ++mm)
#pragma unroll
        for (int nn = 0; nn < 4; ++nn)
          acc[mm][nn] = __builtin_amdgcn_mfma_f32_16x16x32_bf16(af[mm], bfr[nn],
                                                                acc[mm][nn], 0, 0, 0);
    }
  }

  if (EPI == 0) {
    const bool isz = (n0 < DI);
#pragma unroll
    for (int P = 0; P < 2; ++P) {
      __syncthreads();
      u16* Oh = pool;  // [64][136]
      if (wr == P) {
#pragma unroll
        for (int mm = 0; mm < 4; ++mm)
#pragma unroll
          for (int i = 0; i < 4; ++i) {
            int rloc = mm * 16 + oct * 4 + i;
#pragma unroll
            for (int nn = 0; nn < 4; ++nn)
              Oh[rloc * 136 + wc * 64 + nn * 16 + fr] = f2us(acc[mm][nn][i]);
          }
      }
      __syncthreads();
#pragma unroll
      for (int p = 0; p < 4; ++p) {
        int e = p * 256 + t;
        int row = e >> 4, cs = (e & 15) * 8;
        uint4 v = *(const uint4*)&Oh[row * 136 + cs];
        size_t grow = m0 + P * 64 + row;
        int col = n0 + cs;
        if (isz) *(uint4*)&zb[grow * DI + col] = v;
        else     *(uint4*)&xraw[grow * CONVD + (col - DI)] = v;
      }
    }
  } else {
#pragma unroll
    for (int P = 0; P < 2; ++P) {
      __syncthreads();
      float* Of = (float*)pool;  // [64][132]
      if (wr == P) {
#pragma unroll
        for (int mm = 0; mm < 4; ++mm)
#pragma unroll
          for (int i = 0; i < 4; ++i) {
            int rloc = mm * 16 + oct * 4 + i;
#pragma unroll
            for (int nn = 0; nn < 4; ++nn)
              Of[rloc * 132 + wc * 64 + nn * 16 + fr] = acc[mm][nn][i];
          }
      }
      __syncthreads();
#pragma unroll
      for (int p = 0; p < 8; ++p) {
        int e = p * 256 + t;
        int row = e >> 5, c4 = (e & 31) * 4;
        float4 v = *(const float4*)&Of[row * 132 + c4];
        *(float4*)&outf[(size_t)(m0 + P * 64 + row) * DM + n0 + c4] = v;
      }
    }
  }
}

// ---- dt (fp32 exact) + x->bf16 fused ----------------------------------------
__global__ __launch_bounds__(256) void dt_gemm_k(const float* __restrict__ x,
                                                 const float* __restrict__ W,
                                                 const float* __restrict__ dtb,
                                                 float* __restrict__ dtp,
                                                 u16* __restrict__ xb16) {
  __shared__ float xs[8 * 1024];
  const int t = threadIdx.x;
  const int row0 = blockIdx.x * 8;
#pragma unroll
  for (int i = 0; i < 8; ++i) {
    int j4 = i * 256 + t;
    float4 v = *(const float4*)&x[(size_t)row0 * DM + j4 * 4];
    *(float4*)&xs[j4 * 4] = v;
    u32 lo = (u32)f2us(v.x) | ((u32)f2us(v.y) << 16);
    u32 hi = (u32)f2us(v.z) | ((u32)f2us(v.w) << 16);
    *(uint2*)&xb16[(size_t)row0 * DM + j4 * 4] = make_uint2(lo, hi);
  }
  __syncthreads();
  const int r = t >> 5, h = t & 31;
  float a0 = 0.f, a1 = 0.f, a2 = 0.f, a3 = 0.f;
  const float* wcol = W + (DI + CONVD) + h;
  const float* xr = &xs[r * 1024];
  for (int k = 0; k < 1024; k += 4) {
    float4 xv = *(const float4*)&xr[k];
    a0 += xv.x * wcol[(size_t)(k + 0) * DPROJ];
    a1 += xv.y * wcol[(size_t)(k + 1) * DPROJ];
    a2 += xv.z * wcol[(size_t)(k + 2) * DPROJ];
    a3 += xv.w * wcol[(size_t)(k + 3) * DPROJ];
  }
  float v = (a0 + a1) + (a2 + a3) + dtb[h];
  dtp[(size_t)(row0 + r) * NH + h] = (v > 20.0f) ? v : log1pf(__expf(v));
}

// ---- causal depthwise conv(4) + SiLU ----------------------------------------
__global__ __launch_bounds__(256) void conv_silu_k(const u16* __restrict__ xraw,
                                                   const float* __restrict__ cw,
                                                   const float* __restrict__ cb,
                                                   u16* __restrict__ xbc) {
  int idx = blockIdx.x * 256 + threadIdx.x;
  int ch8 = idx % (CONVD / 8);
  int bl = idx / (CONVD / 8);
  int l = bl & (L_ - 1);
  int ch = ch8 * 8;
  const u16* src = xraw + (size_t)bl * CONVD + ch;
  float a[8], o[8];
#pragma unroll
  for (int qq = 0; qq < 8; ++qq) a[qq] = cb[ch + qq];
  float w0[8], w1[8], w2[8], w3[8];
#pragma unroll
  for (int qq = 0; qq < 8; ++qq) {
    float4 w = *(const float4*)&cw[(ch + qq) * 4];
    w0[qq] = w.x; w1[qq] = w.y; w2[qq] = w.z; w3[qq] = w.w;
  }
  if (l >= 3) {
    uint4 v = *(const uint4*)&src[-3 * CONVD]; unpack8(v, o);
#pragma unroll
    for (int qq = 0; qq < 8; ++qq) a[qq] += o[qq] * w0[qq];
  }
  if (l >= 2) {
    uint4 v = *(const uint4*)&src[-2 * CONVD]; unpack8(v, o);
#pragma unroll
    for (int qq = 0; qq < 8; ++qq) a[qq] += o[qq] * w1[qq];
  }
  if (l >= 1) {
    uint4 v = *(const uint4*)&src[-CONVD]; unpack8(v, o);
#pragma unroll
    for (int qq = 0; qq < 8; ++qq) a[qq] += o[qq] * w2[qq];
  }
  {
    uint4 v = *(const uint4*)&src[0]; unpack8(v, o);
#pragma unroll
    for (int qq = 0; qq < 8; ++qq) a[qq] += o[qq] * w3[qq];
  }
  uint4 ov;
  ov.x = (u32)f2us(silu_(a[0])) | ((u32)f2us(silu_(a[1])) << 16);
  ov.y = (u32)f2us(silu_(a[2])) | ((u32)f2us(silu_(a[3])) << 16);
  ov.z = (u32)f2us(silu_(a[4])) | ((u32)f2us(silu_(a[5])) << 16);
  ov.w = (u32)f2us(silu_(a[6])) | ((u32)f2us(silu_(a[7])) << 16);
  *(uint4*)&xbc[(size_t)bl * CONVD + ch] = ov;
}

// ---- per-(b,h,c) cumsum of dt*A ---------------------------------------------
__global__ __launch_bounds__(256) void acs_k(const float* __restrict__ dtp,
                                             const float* __restrict__ A_log,
                                             float* __restrict__ Acs) {
  const int t = threadIdx.x;
  const int lane = t & 63, wv = t >> 6;
  const int idx = blockIdx.x * 4 + wv;
  const int h = (idx >> 4) & (NH - 1);
  const int c = idx & (NC - 1);
  const int b = idx >> 9;
  const float Ah = -__expf(A_log[h]);
  const size_t base = ((size_t)b * L_ + c * CH + lane * 4) * NH + h;
  float v0 = dtp[base] * Ah;
  float v1 = dtp[base + NH] * Ah;
  float v2 = dtp[base + 2 * NH] * Ah;
  float v3 = dtp[base + 3 * NH] * Ah;
  float c1 = v0 + v1, c2 = c1 + v2, c3 = c2 + v3;
  float tot = c3;
#pragma unroll
  for (int off = 1; off < 64; off <<= 1) {
    float p = __shfl_up(tot, off, 64);
    if (lane >= off) tot += p;
  }
  float excl = tot - c3;
  float4 ov = make_float4(excl + v0, excl + c1, excl + c2, excl + c3);
  *(float4*)&Acs[(size_t)idx * CH + lane * 4] = ov;
}

// ---- chunk end-states via MFMA -> bf16 --------------------------------------
#define SLP 72
__global__ __launch_bounds__(256) void states_k(const u16* __restrict__ xbc,
                                                const float* __restrict__ dtp,
                                                const float* __restrict__ Acs,
                                                u16* __restrict__ st16) {
  __shared__ u16 BtT[128 * SLP];
  __shared__ u16 XtT[64 * SLP];
  const int t = threadIdx.x;
  const int wv = t >> 6, lane = t & 63;
  const int fr = lane & 15, oct = lane >> 4;
  const int h = blockIdx.x & 31, c = (blockIdx.x >> 5) & 15, b = blockIdx.x >> 9;
  const size_t acsb = (((size_t)b * NH + h) * NC + c) * CH;
  const float acs_last = Acs[acsb + (CH - 1)];
  const size_t rowbase = (size_t)b * L_ + c * CH;

  f32x4 acc[2][4];
#pragma unroll
  for (int mt = 0; mt < 2; ++mt)
#pragma unroll
    for (int pt = 0; pt < 4; ++pt) acc[mt][pt] = (f32x4){0.f, 0.f, 0.f, 0.f};

  for (int lt = 0; lt < 4; ++lt) {
    __syncthreads();
#pragma unroll
    for (int i = 0; i < 4; ++i) {
      int ci = i * 256 + t;
      int l = ci >> 4, nk = ci & 15;
      uint4 v = *(const uint4*)&xbc[(rowbase + lt * 64 + l) * CONVD + DI + nk * 8];
      u16 p8[8];
      p8[0] = (u16)(v.x & 0xffffu); p8[1] = (u16)(v.x >> 16);
      p8[2] = (u16)(v.y & 0xffffu); p8[3] = (u16)(v.y >> 16);
      p8[4] = (u16)(v.z & 0xffffu); p8[5] = (u16)(v.z >> 16);
      p8[6] = (u16)(v.w & 0xffffu); p8[7] = (u16)(v.w >> 16);
#pragma unroll
      for (int qq = 0; qq < 8; ++qq) {
        int r = nk * 8 + qq;
        BtT[r * SLP + ((((l >> 3) ^ (r >> 3)) & 7) << 3) + (l & 7)] = p8[qq];
      }
    }
#pragma unroll
    for (int i = 0; i < 2; ++i) {
      int ci = i * 256 + t;
      int l = ci >> 3, pk = ci & 7;
      size_t row = rowbase + lt * 64 + l;
      uint4 v = *(const uint4*)&xbc[row * CONVD + h * HD + pk * 8];
      float d = dtp[row * NH + h] * __expf(acs_last - Acs[acsb + lt * 64 + l]);
      float o[8]; unpack8(v, o);
#pragma unroll
      for (int qq = 0; qq < 8; ++qq) {
        int r = pk * 8 + qq;
        XtT[r * SLP + ((((l >> 3) ^ (r >> 3)) & 7) << 3) + (l & 7)] = f2us(o[qq] * d);
      }
    }
    __syncthreads();
    __builtin_amdgcn_s_setprio(1);
#pragma unroll
    for (int ks = 0; ks < 2; ++ks) {
      bf16x8 afr[2], bfr[4];
#pragma unroll
      for (int mt = 0; mt < 2; ++mt) {
        int r = wv * 32 + mt * 16 + fr;
        afr[mt] = *(const bf16x8*)&BtT[r * SLP + ((((ks * 4 + oct) ^ (r >> 3)) & 7) << 3)];
      }
#pragma unroll
      for (int pt = 0; pt < 4; ++pt) {
        int r = pt * 16 + fr;
        bfr[pt] = *(const bf16x8*)&XtT[r * SLP + ((((ks * 4 + oct) ^ (r >> 3)) & 7) << 3)];
      }
#pragma unroll
      for (int mt = 0; mt < 2; ++mt)
#pragma unroll
        for (int pt = 0; pt < 4; ++pt)
          acc[mt][pt] = __builtin_amdgcn_mfma_f32_16x16x32_bf16(afr[mt], bfr[pt],
                                                                acc[mt][pt], 0, 0, 0);
    }
    __builtin_amdgcn_s_setprio(0);
  }
  size_t sbase = (((size_t)b * NC + c) * NH + h) * (size_t)(HD * DS);
#pragma unroll
  for (int mt = 0; mt < 2; ++mt)
#pragma unroll
    for (int pt = 0; pt < 4; ++pt) {
      int p = pt * 16 + fr;
      int n0 = wv * 32 + mt * 16 + oct * 4;
      u32 lo = (u32)f2us(acc[mt][pt][0]) | ((u32)f2us(acc[mt][pt][1]) << 16);
      u32 hi = (u32)f2us(acc[mt][pt][2]) | ((u32)f2us(acc[mt][pt][3]) << 16);
      *(uint2*)&st16[sbase + (size_t)p * DS + n0] = make_uint2(lo, hi);
    }
}

// ---- inter-chunk scan (bf16 states, fp32 carry) -----------------------------
__global__ __launch_bounds__(256) void scan_k(u16* __restrict__ st16,
                                              const float* __restrict__ Acs) {
  const int t = threadIdx.x;
  const int seg = blockIdx.x & 15;
  const int bh = blockIdx.x >> 4;
  const int h = bh & 31, b = bh >> 5;
  const int e2 = seg * 256 + t;
  const size_t acssb = ((size_t)b * NH + h) * NC * CH;
  float run0 = 0.0f, run1 = 0.0f;
#pragma unroll
  for (int c = 0; c < NC; ++c) {
    float dAl = __expf(Acs[acssb + (size_t)c * CH + (CH - 1)]);
    size_t e = (((size_t)b * NC + c) * NH + h) * (size_t)(HD * DS) + e2 * 2;
    u32 v = *(const u32*)&st16[e];
    float s0 = us2f((u16)(v & 0xffffu)), s1 = us2f((u16)(v >> 16));
    *(u32*)&st16[e] = (u32)f2us(run0) | ((u32)f2us(run1) << 16);
    run0 = fmaf(dAl, run0, s0);
    run1 = fmaf(dAl, run1, s1);
  }
}

// ---- merged SSD: one 8-wave block per (b,c,h) -------------------------------
#define SP 72
#define XOFF 8192
#define POFF 12800
__global__ __launch_bounds__(512, 4) void ssd_out_k(const u16* __restrict__ xbc,
                                                    const float* __restrict__ dtp,
                                                    const float* __restrict__ Acs,
                                                    const u16* __restrict__ st16,
                                                    const float* __restrict__ Dvec,
                                                    u16* __restrict__ y) {
  __shared__ u16 pool[31232];
  __shared__ float acs_s[256];
  const int t = threadIdx.x;
  const int w = t >> 6, lane = t & 63;
  const int fr = lane & 15, oct = lane >> 4;
  const int h = blockIdx.x & 31, c = (blockIdx.x >> 5) & 15, b = blockIdx.x >> 9;
  const size_t acsb = (((size_t)b * NH + h) * NC + c) * CH;
  const size_t rowbase = (size_t)b * L_ + c * CH;
  if (t < 256) acs_s[t] = Acs[acsb + t];
  const size_t sb = (((size_t)b * NC + c) * NH + h) * (size_t)(HD * DS);
#pragma unroll
  for (int i = 0; i < 2; ++i) {
    int ci = i * 512 + t; int p = ci >> 4, nk = ci & 15;
    uint4 v = *(const uint4*)&st16[sb + (size_t)p * DS + nk * 8];
    *(uint4*)&pool[p * 136 + nk * 8] = v;
  }
  __syncthreads();
  bf16x8 ca[2][4];
#pragma unroll
  for (int mt = 0; mt < 2; ++mt)
#pragma unroll
    for (int kk = 0; kk < 4; ++kk)
      ca[mt][kk] = *(const bf16x8*)&xbc[(rowbase + w * 32 + mt * 16 + fr) * CONVD +
                                        DI + DS + kk * 32 + oct * 8];
  f32x4 acc_y[2][4];
#pragma unroll
  for (int mt = 0; mt < 2; ++mt)
#pragma unroll
    for (int pp4 = 0; pp4 < 4; ++pp4) acc_y[mt][pp4] = (f32x4){0.f, 0.f, 0.f, 0.f};

  {
    float eL0 = __expf(acs_s[w * 32 + fr]);
    float eL1 = __expf(acs_s[w * 32 + 16 + fr]);
    __builtin_amdgcn_s_setprio(1);
#pragma unroll
    for (int kk = 0; kk < 4; ++kk) {
      bf16x8 c0 = scale8(ca[0][kk], eL0);
      bf16x8 c1 = scale8(ca[1][kk], eL1);
#pragma unroll
      for (int pp4 = 0; pp4 < 4; ++pp4) {
        bf16x8 sf = *(const bf16x8*)&pool[(pp4 * 16 + fr) * 136 + kk * 32 + oct * 8];
        acc_y[0][pp4] = __builtin_amdgcn_mfma_f32_16x16x32_bf16(c0, sf, acc_y[0][pp4], 0, 0, 0);
        acc_y[1][pp4] = __builtin_amdgcn_mfma_f32_16x16x32_bf16(c1, sf, acc_y[1][pp4], 0, 0, 0);
      }
    }
    __builtin_amdgcn_s_setprio(0);
  }

  const int stmax = w >> 1, delta = (w & 1) << 5;
  for (int st = 0; st < 4; ++st) {
    __syncthreads();
#pragma unroll
    for (int i = 0; i < 2; ++i) {
      int ci = i * 512 + t; int ll = ci >> 4, ck = ci & 15;
      uint4 v = *(const uint4*)&xbc[(rowbase + st * 64 + ll) * CONVD + DI + ck * 8];
      *(uint4*)&pool[ll * 128 + ((ck * 8) ^ ((ll & 7) << 3))] = v;
    }
    {
      int s = t >> 3, pk = t & 7;
      size_t row = rowbase + st * 64 + s;
      uint4 v = *(const uint4*)&xbc[row * CONVD + h * HD + pk * 8];
      float d = dtp[row * NH + h];
      float o[8]; unpack8(v, o);
#pragma unroll
      for (int qq = 0; qq < 8; ++qq) {
        int r = pk * 8 + qq;
        pool[XOFF + r * SP + ((((s >> 3) ^ (r >> 3)) & 7) << 3) + (s & 7)] = f2us(o[qq] * d);
      }
    }
    __syncthreads();
    if (st > stmax) continue;
    const bool diag = (st == stmax);
#pragma unroll
    for (int ss4 = 0; ss4 < 4; ++ss4) {
      bf16x8 bbf[4];
#pragma unroll
      for (int kk = 0; kk < 4; ++kk)
        bbf[kk] = *(const bf16x8*)&pool[(ss4 * 16 + fr) * 128 +
                                        ((kk * 32 + oct * 8) ^ ((fr & 7) << 3))];
      int s_in = ss4 * 16 + fr;
      float aS = acs_s[st * 64 + s_in];
#pragma unroll
      for (int mt = 0; mt < 2; ++mt) {
        f32x4 sacc = (f32x4){0.f, 0.f, 0.f, 0.f};
        __builtin_amdgcn_s_setprio(1);
#pragma unroll
        for (int kk = 0; kk < 4; ++kk)
          sacc = __builtin_amdgcn_mfma_f32_16x16x32_bf16(ca[mt][kk], bbf[kk], sacc, 0, 0, 0);
        __builtin_amdgcn_s_setprio(0);
#pragma unroll
        for (int i = 0; i < 4; ++i) {
          int r = mt * 16 + oct * 4 + i;
          float aL = acs_s[w * 32 + r];
          float wgt = (!diag || (s_in <= r + delta)) ? __expf(aL - aS) : 0.0f;
          pool[POFF + w * 2304 + r * SP + s_in] = f2us(sacc[i] * wgt);
        }
      }
    }
    bf16x8 pa[2][2];
#pragma unroll
    for (int mt = 0; mt < 2; ++mt)
#pragma unroll
      for (int k2 = 0; k2 < 2; ++k2)
        pa[mt][k2] = *(const bf16x8*)&pool[POFF + w * 2304 + (mt * 16 + fr) * SP +
                                           k2 * 32 + oct * 8];
    __builtin_amdgcn_s_setprio(1);
#pragma unroll
    for (int pp4 = 0; pp4 < 4; ++pp4) {
      int rx = pp4 * 16 + fr, xg = rx >> 3;
      bf16x8 xb0 = *(const bf16x8*)&pool[XOFF + rx * SP + (((oct) ^ xg) & 7) * 8];
      bf16x8 xb1 = *(const bf16x8*)&pool[XOFF + rx * SP + (((4 + oct) ^ xg) & 7) * 8];
#pragma unroll
      for (int mt = 0; mt < 2; ++mt) {
        acc_y[mt][pp4] = __builtin_amdgcn_mfma_f32_16x16x32_bf16(pa[mt][0], xb0, acc_y[mt][pp4], 0, 0, 0);
        acc_y[mt][pp4] = __builtin_amdgcn_mfma_f32_16x16x32_bf16(pa[mt][1], xb1, acc_y[mt][pp4], 0, 0, 0);
      }
    }
    __builtin_amdgcn_s_setprio(0);
  }

  const float Dh = Dvec[h];
#pragma unroll
  for (int mt = 0; mt < 2; ++mt)
#pragma unroll
    for (int i = 0; i < 4; ++i) {
      size_t row = rowbase + w * 32 + mt * 16 + oct * 4 + i;
#pragma unroll
      for (int pp4 = 0; pp4 < 4; ++pp4) {
        int col = h * HD + pp4 * 16 + fr;
        float xs = us2f(xbc[row * CONVD + col]);
        y[row * DI + col] = f2us(acc_y[mt][pp4][i] + Dh * xs);
      }
    }
}

// ---- gated RMSNorm in place on y (bf16) -------------------------------------
__global__ __launch_bounds__(256) void gnorm_k(const u16* __restrict__ zb,
                                               const float* __restrict__ nw,
                                               u16* __restrict__ y) {
  const int row = blockIdx.x, t = threadIdx.x;
  const u16* zr = zb + (size_t)row * DI;
  u16* yr = y + (size_t)row * DI;
  uint4 zv = *(const uint4*)&zr[t * 8];
  uint4 yv = *(const uint4*)&yr[t * 8];
  float uz[8], uy[8];
  unpack8(zv, uz); unpack8(yv, uy);
  float u[8], ssum = 0.0f;
#pragma unroll
  for (int j = 0; j < 8; ++j) { u[j] = uy[j] * silu_(uz[j]); ssum += u[j] * u[j]; }
#pragma unroll
  for (int off = 32; off >= 1; off >>= 1) ssum += __shfl_xor(ssum, off, 64);
  __shared__ float red[4];
  if ((t & 63) == 0) red[t >> 6] = ssum;
  __syncthreads();
  float sc = rsqrtf((red[0] + red[1] + red[2] + red[3]) * (1.0f / DI) + 1e-5f);
  float4 w0 = *(const float4*)&nw[t * 8];
  float4 w1 = *(const float4*)&nw[t * 8 + 4];
  float o0 = u[0] * sc * w0.x, o1 = u[1] * sc * w0.y, o2 = u[2] * sc * w0.z, o3 = u[3] * sc * w0.w;
  float o4 = u[4] * sc * w1.x, o5 = u[5] * sc * w1.y, o6 = u[6] * sc * w1.z, o7 = u[7] * sc * w1.w;
  uint4 ov;
  ov.x = (u32)f2us(o0) | ((u32)f2us(o1) << 16);
  ov.y = (u32)f2us(o2) | ((u32)f2us(o3) << 16);
  ov.z = (u32)f2us(o4) | ((u32)f2us(o5) << 16);
  ov.w = (u32)f2us(o6) | ((u32)f2us(o7) << 16);
  *(uint4*)&yr[t * 8] = ov;
}

extern "C" void kernel_launch(void* const* d_in, const int* in_sizes, int n_in,
                              void* d_out, int out_size, void* d_ws, size_t ws_size,
                              hipStream_t stream) {
  const float* x      = (const float*)d_in[0];
  const float* W_in   = (const float*)d_in[1];
  const float* conv_w = (const float*)d_in[2];
  const float* conv_b = (const float*)d_in[3];
  const float* dt_b   = (const float*)d_in[4];
  const float* A_log  = (const float*)d_in[5];
  const float* Dvec   = (const float*)d_in[6];
  const float* norm_w = (const float*)d_in[7];
  const float* W_out  = (const float*)d_in[8];
  float* out = (float*)d_out;

  u16* zb       = (u16*)d_ws;                              // 33.55 MB
  u16* xbc      = zb + (size_t)B_ * L_ * DI;               // 37.75 MB
  float* dtp    = (float*)(xbc + (size_t)B_ * L_ * CONVD); // 1.05 MB
  float* Acs    = dtp + (size_t)B_ * L_ * NH;              // 1.05 MB
  u16* stregion = (u16*)(Acs + (size_t)B_ * NH * L_);      // 33.55 MB region
  u16* uni      = stregion + (size_t)B_ * NC * NH * HD * DS * 2;  // 37.75 MB
  u16* xraw = uni;
  u16* y    = uni;

  u16* xb16     = stregion;
  u16* wint     = stregion + (size_t)B_ * L_ * DM;
  u16* states16 = stregion;
  u16* woutt    = stregion;

  const int Mrows = B_ * L_;

  dt_gemm_k<<<Mrows / 8, 256, 0, stream>>>(x, W_in, dt_b, dtp, xb16);
  cvt_t_k<<<dim3(NGEMM / 64, DM / 64), 256, 0, stream>>>(W_in, wint, DPROJ, DM);

  const int nwg_in = (Mrows / 128) * (NGEMM / 128);   // 2176
  gemm_bf16_k<DM, NGEMM / 128, 0><<<nwg_in, 256, 0, stream>>>(
      xb16, wint, zb, xraw, nullptr, nwg_in);

  conv_silu_k<<<(Mrows * (CONVD / 8)) / 256, 256, 0, stream>>>(xraw, conv_w, conv_b, xbc);
  acs_k<<<(B_ * NH * NC) / 4, 256, 0, stream>>>(dtp, A_log, Acs);
  states_k<<<B_ * NC * NH, 256, 0, stream>>>(xbc, dtp, Acs, states16);
  scan_k<<<B_ * NH * 16, 256, 0, stream>>>(states16, Acs);
  ssd_out_k<<<B_ * NC * NH, 512, 0, stream>>>(xbc, dtp, Acs, states16, Dvec, y);
  gnorm_k<<<Mrows, 256, 0, stream>>>(zb, norm_w, y);

  cvt_t_k<<<dim3(DM / 64, DI / 64), 256, 0, stream>>>(W_out, woutt, DM, DI);
  const int nwg_out = (Mrows / 128) * (DM / 128);     // 512
  gemm_bf16_k<DI, DM / 128, 1><<<nwg_out, 256, 0, stream>>>(
      y, woutt, nullptr, nullptr, out, nwg_out);
}

// Round 11
// 345.923 us; speedup vs baseline: 1.0609x; 1.0062x over previous
//
#include <hip/hip_runtime.h>
#include <math.h>

#define B_ 2
#define L_ 4096
#define DM 1024
#define DI 2048
#define HD 64
#define NH 32
#define DS 128
#define CH 256
#define NC 16
#define DPROJ 4384   // 2*DI + 2*DS + NH
#define CONVD 2304   // DI + 2*DS
#define NGEMM 4352   // z + xBC columns (dt handled separately)

typedef unsigned short u16;
typedef unsigned int u32;
typedef __attribute__((ext_vector_type(8))) short bf16x8;
typedef __attribute__((ext_vector_type(4))) float f32x4;

__device__ __forceinline__ float silu_(float x) { return x / (1.0f + __expf(-x)); }
__device__ __forceinline__ float us2f(u16 u) {
  union { u32 i; float f; } c; c.i = ((u32)u) << 16; return c.f;
}
__device__ __forceinline__ u16 f2us(float f) {
  union { float f; u32 i; } c; c.f = f;
  u32 i = c.i;
  return (u16)((i + 0x7FFFu + ((i >> 16) & 1u)) >> 16);  // round-nearest-even
}
__device__ __forceinline__ void unpack8(uint4 v, float* o) {
  o[0] = us2f(v.x & 0xffffu); o[1] = us2f(v.x >> 16);
  o[2] = us2f(v.y & 0xffffu); o[3] = us2f(v.y >> 16);
  o[4] = us2f(v.z & 0xffffu); o[5] = us2f(v.z >> 16);
  o[6] = us2f(v.w & 0xffffu); o[7] = us2f(v.w >> 16);
}
__device__ __forceinline__ void unpk16(uint4 v, u16* o) {
  o[0] = (u16)(v.x & 0xffffu); o[1] = (u16)(v.x >> 16);
  o[2] = (u16)(v.y & 0xffffu); o[3] = (u16)(v.y >> 16);
  o[4] = (u16)(v.z & 0xffffu); o[5] = (u16)(v.z >> 16);
  o[6] = (u16)(v.w & 0xffffu); o[7] = (u16)(v.w >> 16);
}
__device__ __forceinline__ bf16x8 scale8(bf16x8 a, float s) {
  bf16x8 r;
#pragma unroll
  for (int j = 0; j < 8; ++j) r[j] = (short)f2us(us2f((u16)a[j]) * s);
  return r;
}
__device__ __forceinline__ void gload16(const u16* g, u16* l) {
  __builtin_amdgcn_global_load_lds(
      (const __attribute__((address_space(1))) void*)g,
      (__attribute__((address_space(3))) void*)l, 16, 0, 0);
}

// ---- transpose + convert: Wt[n][k] = (bf16) W[k][n] -------------------------
__global__ __launch_bounds__(256) void cvt_t_k(const float* __restrict__ W,
                                               u16* __restrict__ Wt,
                                               int ldW, int ldT) {
  __shared__ float tile[64][65];
  const int t = threadIdx.x;
  const int n0 = blockIdx.x * 64, k0 = blockIdx.y * 64;
#pragma unroll
  for (int i = 0; i < 16; ++i) {
    int j = i * 256 + t;
    int kk = j >> 6, nn = j & 63;
    tile[kk][nn] = W[(size_t)(k0 + kk) * ldW + n0 + nn];
  }
  __syncthreads();
#pragma unroll
  for (int i = 0; i < 16; ++i) {
    int j = i * 256 + t;
    int nn = j >> 6, kk = j & 63;
    Wt[(size_t)(n0 + nn) * ldT + k0 + kk] = f2us(tile[kk][nn]);
  }
}

// ==== 256x128 bf16 MFMA GEMM (in-proj): m97 structure, higher reuse =========
// 8 waves (4m x 2n), BK=64, LDS 48KB single-buffered, 2 barriers/K-step.
// Staging ratio 384 rows per 256x128 output (vs 512 for 2x 128^2): +33% AI.
__global__ __launch_bounds__(512, 4) void gemm_in_k(const u16* __restrict__ A,
                                                    const u16* __restrict__ Bt,
                                                    u16* __restrict__ zb,
                                                    u16* __restrict__ xraw,
                                                    int nwg) {
  __shared__ u16 pool[24576];   // Al[256][64] @0, Bl[128][64] @16384
  u16* Al = pool;
  u16* Bl = pool + 16384;
  const int t = threadIdx.x;
  const int w = t >> 6, lane = t & 63;
  const int fr = lane & 15, oct = lane >> 4;
  const int wm = w >> 1, wn = w & 1;
  const int q = nwg >> 3;
  const int wg = (blockIdx.x & 7) * q + (blockIdx.x >> 3);
  const int bm = wg / (NGEMM / 128), bn = wg % (NGEMM / 128);
  const int m0 = bm * 256, n0 = bn * 128;
  const int lr = lane >> 3, ls = lane & 7;
  const int gslot = (ls ^ lr) * 8;   // XOR involution: LDS[r][s] = G[r][s^(r&7)]

  f32x4 acc[4][4];
#pragma unroll
  for (int mm = 0; mm < 4; ++mm)
#pragma unroll
    for (int nn = 0; nn < 4; ++nn) acc[mm][nn] = (f32x4){0.f, 0.f, 0.f, 0.f};

  for (int k0 = 0; k0 < DM; k0 += 64) {
    if (k0) __syncthreads();
#pragma unroll
    for (int i = 0; i < 4; ++i) {
      const int rowA = w * 32 + i * 8;
      gload16(&A[(size_t)(m0 + rowA + lr) * DM + k0 + gslot], &Al[rowA * 64]);
    }
#pragma unroll
    for (int i = 0; i < 2; ++i) {
      const int rowB = w * 16 + i * 8;
      gload16(&Bt[(size_t)(n0 + rowB + lr) * DM + k0 + gslot], &Bl[rowB * 64]);
    }
    __syncthreads();
#pragma unroll
    for (int kk = 0; kk < 2; ++kk) {
      bf16x8 af[4], bfr[4];
#pragma unroll
      for (int mm = 0; mm < 4; ++mm)
        af[mm] = *(const bf16x8*)&Al[(wm * 64 + mm * 16 + fr) * 64 +
                                     (((kk * 4 + oct) ^ (fr & 7)) * 8)];
#pragma unroll
      for (int nn = 0; nn < 4; ++nn)
        bfr[nn] = *(const bf16x8*)&Bl[(wn * 64 + nn * 16 + fr) * 64 +
                                      (((kk * 4 + oct) ^ (fr & 7)) * 8)];
      __builtin_amdgcn_s_setprio(1);
#pragma unroll
      for (int mm = 0; mm < 4; ++mm)
#pragma unroll
        for (int nn = 0; nn < 4; ++nn)
          acc[mm][nn] = __builtin_amdgcn_mfma_f32_16x16x32_bf16(af[mm], bfr[nn],
                                                                acc[mm][nn], 0, 0, 0);
      __builtin_amdgcn_s_setprio(0);
    }
  }

  // coalesced epilogue: 4 passes of 64 rows via LDS [64][136]
  const bool isz = (n0 < DI);
  u16* Oh = pool;
#pragma unroll
  for (int P = 0; P < 4; ++P) {
    __syncthreads();
    if (wm == P) {
#pragma unroll
      for (int mm = 0; mm < 4; ++mm)
#pragma unroll
        for (int i = 0; i < 4; ++i) {
          int rloc = mm * 16 + oct * 4 + i;
#pragma unroll
          for (int nn = 0; nn < 4; ++nn)
            Oh[rloc * 136 + wn * 64 + nn * 16 + fr] = f2us(acc[mm][nn][i]);
        }
    }
    __syncthreads();
#pragma unroll
    for (int p = 0; p < 2; ++p) {
      int e = p * 512 + t;
      int row = e >> 4, cs = (e & 15) * 8;
      uint4 v = *(const uint4*)&Oh[row * 136 + cs];
      size_t grow = m0 + P * 64 + row;
      int col = n0 + cs;
      if (isz) *(uint4*)&zb[grow * DI + col] = v;
      else     *(uint4*)&xraw[grow * CONVD + (col - DI)] = v;
    }
  }
}

// ---- bf16 MFMA GEMM 128x128 (out-proj, fp32 out) ----------------------------
template <int KDIM, int NTN>
__global__ __launch_bounds__(256) void gemm_bf16_k(const u16* __restrict__ A,
                                                   const u16* __restrict__ Bt,
                                                   float* __restrict__ outf,
                                                   int nwg) {
  __shared__ u16 pool[17408];
  u16* Al = pool;
  u16* Bl = pool + 8192;
  const int t = threadIdx.x;
  const int wv = t >> 6, lane = t & 63;
  const int fr = lane & 15, oct = lane >> 4;
  const int wr = wv >> 1, wc = wv & 1;
  const int q = nwg >> 3;
  const int wg = (blockIdx.x & 7) * q + (blockIdx.x >> 3);
  const int bm = wg / NTN, bn = wg % NTN;
  const int m0 = bm * 128, n0 = bn * 128;

  const int lr = lane >> 3, ls = lane & 7;
  const int gslot = (ls ^ lr) * 8;

  f32x4 acc[4][4];
#pragma unroll
  for (int mm = 0; mm < 4; ++mm)
#pragma unroll
    for (int nn = 0; nn < 4; ++nn) acc[mm][nn] = (f32x4){0.f, 0.f, 0.f, 0.f};

  for (int k0 = 0; k0 < KDIM; k0 += 64) {
    if (k0) __syncthreads();
#pragma unroll
    for (int i = 0; i < 4; ++i) {
      const int rowA = wv * 32 + i * 8;
      gload16(&A[(size_t)(m0 + rowA + lr) * KDIM + k0 + gslot], &Al[rowA * 64]);
      gload16(&Bt[(size_t)(n0 + rowA + lr) * KDIM + k0 + gslot], &Bl[rowA * 64]);
    }
    __syncthreads();
#pragma unroll
    for (int kk = 0; kk < 2; ++kk) {
      bf16x8 af[4], bfr[4];
#pragma unroll
      for (int mm = 0; mm < 4; ++mm)
        af[mm] = *(const bf16x8*)&Al[(wr * 64 + mm * 16 + fr) * 64 +
                                     (((kk * 4 + oct) ^ (fr & 7)) * 8)];
#pragma unroll
      for (int nn = 0; nn < 4; ++nn)
        bfr[nn] = *(const bf16x8*)&Bl[(wc * 64 + nn * 16 + fr) * 64 +
                                      (((kk * 4 + oct) ^ (fr & 7)) * 8)];
#pragma unroll
      for (int mm = 0; mm < 4; ++mm)
#pragma unroll
        for (int nn = 0; nn < 4; ++nn)
          acc[mm][nn] = __builtin_amdgcn_mfma_f32_16x16x32_bf16(af[mm], bfr[nn],
                                                                acc[mm][nn], 0, 0, 0);
    }
  }

#pragma unroll
  for (int P = 0; P < 2; ++P) {
    __syncthreads();
    float* Of = (float*)pool;  // [64][132]
    if (wr == P) {
#pragma unroll
      for (int mm = 0; mm < 4; ++mm)
#pragma unroll
        for (int i = 0; i < 4; ++i) {
          int rloc = mm * 16 + oct * 4 + i;
#pragma unroll
          for (int nn = 0; nn < 4; ++nn)
            Of[rloc * 132 + wc * 64 + nn * 16 + fr] = acc[mm][nn][i];
        }
    }
    __syncthreads();
#pragma unroll
    for (int p = 0; p < 8; ++p) {
      int e = p * 256 + t;
      int row = e >> 5, c4 = (e & 31) * 4;
      float4 v = *(const float4*)&Of[row * 132 + c4];
      *(float4*)&outf[(size_t)(m0 + P * 64 + row) * DM + n0 + c4] = v;
    }
  }
}

// ---- dt (fp32 exact) + x->bf16 fused ----------------------------------------
__global__ __launch_bounds__(256) void dt_gemm_k(const float* __restrict__ x,
                                                 const float* __restrict__ W,
                                                 const float* __restrict__ dtb,
                                                 float* __restrict__ dtp,
                                                 u16* __restrict__ xb16) {
  __shared__ float xs[8 * 1024];
  const int t = threadIdx.x;
  const int row0 = blockIdx.x * 8;
#pragma unroll
  for (int i = 0; i < 8; ++i) {
    int j4 = i * 256 + t;
    float4 v = *(const float4*)&x[(size_t)row0 * DM + j4 * 4];
    *(float4*)&xs[j4 * 4] = v;
    u32 lo = (u32)f2us(v.x) | ((u32)f2us(v.y) << 16);
    u32 hi = (u32)f2us(v.z) | ((u32)f2us(v.w) << 16);
    *(uint2*)&xb16[(size_t)row0 * DM + j4 * 4] = make_uint2(lo, hi);
  }
  __syncthreads();
  const int r = t >> 5, h = t & 31;
  float a0 = 0.f, a1 = 0.f, a2 = 0.f, a3 = 0.f;
  const float* wcol = W + (DI + CONVD) + h;
  const float* xr = &xs[r * 1024];
  for (int k = 0; k < 1024; k += 4) {
    float4 xv = *(const float4*)&xr[k];
    a0 += xv.x * wcol[(size_t)(k + 0) * DPROJ];
    a1 += xv.y * wcol[(size_t)(k + 1) * DPROJ];
    a2 += xv.z * wcol[(size_t)(k + 2) * DPROJ];
    a3 += xv.w * wcol[(size_t)(k + 3) * DPROJ];
  }
  float v = (a0 + a1) + (a2 + a3) + dtb[h];
  dtp[(size_t)(row0 + r) * NH + h] = (v > 20.0f) ? v : log1pf(__expf(v));
}

// ---- causal depthwise conv(4) + SiLU ----------------------------------------
__global__ __launch_bounds__(256) void conv_silu_k(const u16* __restrict__ xraw,
                                                   const float* __restrict__ cw,
                                                   const float* __restrict__ cb,
                                                   u16* __restrict__ xbc) {
  int idx = blockIdx.x * 256 + threadIdx.x;
  int ch8 = idx % (CONVD / 8);
  int bl = idx / (CONVD / 8);
  int l = bl & (L_ - 1);
  int ch = ch8 * 8;
  const u16* src = xraw + (size_t)bl * CONVD + ch;
  float a[8], o[8];
#pragma unroll
  for (int qq = 0; qq < 8; ++qq) a[qq] = cb[ch + qq];
  float w0[8], w1[8], w2[8], w3[8];
#pragma unroll
  for (int qq = 0; qq < 8; ++qq) {
    float4 w = *(const float4*)&cw[(ch + qq) * 4];
    w0[qq] = w.x; w1[qq] = w.y; w2[qq] = w.z; w3[qq] = w.w;
  }
  if (l >= 3) {
    uint4 v = *(const uint4*)&src[-3 * CONVD]; unpack8(v, o);
#pragma unroll
    for (int qq = 0; qq < 8; ++qq) a[qq] += o[qq] * w0[qq];
  }
  if (l >= 2) {
    uint4 v = *(const uint4*)&src[-2 * CONVD]; unpack8(v, o);
#pragma unroll
    for (int qq = 0; qq < 8; ++qq) a[qq] += o[qq] * w1[qq];
  }
  if (l >= 1) {
    uint4 v = *(const uint4*)&src[-CONVD]; unpack8(v, o);
#pragma unroll
    for (int qq = 0; qq < 8; ++qq) a[qq] += o[qq] * w2[qq];
  }
  {
    uint4 v = *(const uint4*)&src[0]; unpack8(v, o);
#pragma unroll
    for (int qq = 0; qq < 8; ++qq) a[qq] += o[qq] * w3[qq];
  }
  uint4 ov;
  ov.x = (u32)f2us(silu_(a[0])) | ((u32)f2us(silu_(a[1])) << 16);
  ov.y = (u32)f2us(silu_(a[2])) | ((u32)f2us(silu_(a[3])) << 16);
  ov.z = (u32)f2us(silu_(a[4])) | ((u32)f2us(silu_(a[5])) << 16);
  ov.w = (u32)f2us(silu_(a[6])) | ((u32)f2us(silu_(a[7])) << 16);
  *(uint4*)&xbc[(size_t)bl * CONVD + ch] = ov;
}

// ---- per-(b,h,c) cumsum of dt*A ---------------------------------------------
__global__ __launch_bounds__(256) void acs_k(const float* __restrict__ dtp,
                                             const float* __restrict__ A_log,
                                             float* __restrict__ Acs) {
  const int t = threadIdx.x;
  const int lane = t & 63, wv = t >> 6;
  const int idx = blockIdx.x * 4 + wv;
  const int h = (idx >> 4) & (NH - 1);
  const int c = idx & (NC - 1);
  const int b = idx >> 9;
  const float Ah = -__expf(A_log[h]);
  const size_t base = ((size_t)b * L_ + c * CH + lane * 4) * NH + h;
  float v0 = dtp[base] * Ah;
  float v1 = dtp[base + NH] * Ah;
  float v2 = dtp[base + 2 * NH] * Ah;
  float v3 = dtp[base + 3 * NH] * Ah;
  float c1 = v0 + v1, c2 = c1 + v2, c3 = c2 + v3;
  float tot = c3;
#pragma unroll
  for (int off = 1; off < 64; off <<= 1) {
    float p = __shfl_up(tot, off, 64);
    if (lane >= off) tot += p;
  }
  float excl = tot - c3;
  float4 ov = make_float4(excl + v0, excl + c1, excl + c2, excl + c3);
  *(float4*)&Acs[(size_t)idx * CH + lane * 4] = ov;
}

// ---- chunk end-states via MFMA -> bf16 (paired-row u32 transpose writes) ----
#define SLP 72
__global__ __launch_bounds__(256) void states_k(const u16* __restrict__ xbc,
                                                const float* __restrict__ dtp,
                                                const float* __restrict__ Acs,
                                                u16* __restrict__ st16) {
  __shared__ u16 BtT[128 * SLP];
  __shared__ u16 XtT[64 * SLP];
  const int t = threadIdx.x;
  const int wv = t >> 6, lane = t & 63;
  const int fr = lane & 15, oct = lane >> 4;
  const int sw = (blockIdx.x & 7) * 128 + (blockIdx.x >> 3);  // XCD swizzle
  const int h = sw & 31, c = (sw >> 5) & 15, b = sw >> 9;
  const size_t acsb = (((size_t)b * NH + h) * NC + c) * CH;
  const float acs_last = Acs[acsb + (CH - 1)];
  const size_t rowbase = (size_t)b * L_ + c * CH;

  f32x4 acc[2][4];
#pragma unroll
  for (int mt = 0; mt < 2; ++mt)
#pragma unroll
    for (int pt = 0; pt < 4; ++pt) acc[mt][pt] = (f32x4){0.f, 0.f, 0.f, 0.f};

  for (int lt = 0; lt < 4; ++lt) {
    __syncthreads();
    // stage Bt[n][l] = B[l][n], two l-rows per u32 write
#pragma unroll
    for (int i = 0; i < 2; ++i) {
      int ci = i * 256 + t;
      int lp = ci >> 4, nk = ci & 15;
      int l0 = lp * 2;
      const u16* srcp = &xbc[(rowbase + lt * 64 + l0) * CONVD + DI + nk * 8];
      uint4 v0 = *(const uint4*)srcp;
      uint4 v1 = *(const uint4*)(srcp + CONVD);
      u16 a0[8], a1[8];
      unpk16(v0, a0); unpk16(v1, a1);
#pragma unroll
      for (int qq = 0; qq < 8; ++qq) {
        int r = nk * 8 + qq;
        u32 val = (u32)a0[qq] | ((u32)a1[qq] << 16);
        *(u32*)&BtT[r * SLP + ((((l0 >> 3) ^ (r >> 3)) & 7) << 3) + (l0 & 7)] = val;
      }
    }
    // stage Xt[p][l] = x[l][p]*dt[l]*wdec[l], two l-rows per u32 write
    {
      int lp = t >> 3, pk = t & 7;
      int l0 = lp * 2;
      size_t row0 = rowbase + lt * 64 + l0;
      uint4 v0 = *(const uint4*)&xbc[row0 * CONVD + h * HD + pk * 8];
      uint4 v1 = *(const uint4*)&xbc[(row0 + 1) * CONVD + h * HD + pk * 8];
      float d0 = dtp[row0 * NH + h] * __expf(acs_last - Acs[acsb + lt * 64 + l0]);
      float d1 = dtp[(row0 + 1) * NH + h] * __expf(acs_last - Acs[acsb + lt * 64 + l0 + 1]);
      float o0[8], o1[8];
      unpack8(v0, o0); unpack8(v1, o1);
#pragma unroll
      for (int qq = 0; qq < 8; ++qq) {
        int r = pk * 8 + qq;
        u32 val = (u32)f2us(o0[qq] * d0) | ((u32)f2us(o1[qq] * d1) << 16);
        *(u32*)&XtT[r * SLP + ((((l0 >> 3) ^ (r >> 3)) & 7) << 3) + (l0 & 7)] = val;
      }
    }
    __syncthreads();
    __builtin_amdgcn_s_setprio(1);
#pragma unroll
    for (int ks = 0; ks < 2; ++ks) {
      bf16x8 afr[2], bfr[4];
#pragma unroll
      for (int mt = 0; mt < 2; ++mt) {
        int r = wv * 32 + mt * 16 + fr;
        afr[mt] = *(const bf16x8*)&BtT[r * SLP + ((((ks * 4 + oct) ^ (r >> 3)) & 7) << 3)];
      }
#pragma unroll
      for (int pt = 0; pt < 4; ++pt) {
        int r = pt * 16 + fr;
        bfr[pt] = *(const bf16x8*)&XtT[r * SLP + ((((ks * 4 + oct) ^ (r >> 3)) & 7) << 3)];
      }
#pragma unroll
      for (int mt = 0; mt < 2; ++mt)
#pragma unroll
        for (int pt = 0; pt < 4; ++pt)
          acc[mt][pt] = __builtin_amdgcn_mfma_f32_16x16x32_bf16(afr[mt], bfr[pt],
                                                                acc[mt][pt], 0, 0, 0);
    }
    __builtin_amdgcn_s_setprio(0);
  }
  size_t sbase = (((size_t)b * NC + c) * NH + h) * (size_t)(HD * DS);
#pragma unroll
  for (int mt = 0; mt < 2; ++mt)
#pragma unroll
    for (int pt = 0; pt < 4; ++pt) {
      int p = pt * 16 + fr;
      int n0 = wv * 32 + mt * 16 + oct * 4;
      u32 lo = (u32)f2us(acc[mt][pt][0]) | ((u32)f2us(acc[mt][pt][1]) << 16);
      u32 hi = (u32)f2us(acc[mt][pt][2]) | ((u32)f2us(acc[mt][pt][3]) << 16);
      *(uint2*)&st16[sbase + (size_t)p * DS + n0] = make_uint2(lo, hi);
    }
}

// ---- inter-chunk scan (bf16 states, fp32 carry) -----------------------------
__global__ __launch_bounds__(256) void scan_k(u16* __restrict__ st16,
                                              const float* __restrict__ Acs) {
  const int t = threadIdx.x;
  const int seg = blockIdx.x & 15;
  const int bh = blockIdx.x >> 4;
  const int h = bh & 31, b = bh >> 5;
  const int e2 = seg * 256 + t;
  const size_t acssb = ((size_t)b * NH + h) * NC * CH;
  float run0 = 0.0f, run1 = 0.0f;
#pragma unroll
  for (int c = 0; c < NC; ++c) {
    float dAl = __expf(Acs[acssb + (size_t)c * CH + (CH - 1)]);
    size_t e = (((size_t)b * NC + c) * NH + h) * (size_t)(HD * DS) + e2 * 2;
    u32 v = *(const u32*)&st16[e];
    float s0 = us2f((u16)(v & 0xffffu)), s1 = us2f((u16)(v >> 16));
    *(u32*)&st16[e] = (u32)f2us(run0) | ((u32)f2us(run1) << 16);
    run0 = fmaf(dAl, run0, s0);
    run1 = fmaf(dAl, run1, s1);
  }
}

// ---- merged SSD: one 8-wave block per (b,c,h), XCD-swizzled -----------------
#define SP 72
#define XOFF 8192
#define POFF 12800
__global__ __launch_bounds__(512, 4) void ssd_out_k(const u16* __restrict__ xbc,
                                                    const float* __restrict__ dtp,
                                                    const float* __restrict__ Acs,
                                                    const u16* __restrict__ st16,
                                                    const float* __restrict__ Dvec,
                                                    u16* __restrict__ y) {
  __shared__ u16 pool[31232];
  __shared__ float acs_s[256];
  const int t = threadIdx.x;
  const int w = t >> 6, lane = t & 63;
  const int fr = lane & 15, oct = lane >> 4;
  const int sw = (blockIdx.x & 7) * 128 + (blockIdx.x >> 3);  // XCD swizzle
  const int h = sw & 31, c = (sw >> 5) & 15, b = sw >> 9;
  const size_t acsb = (((size_t)b * NH + h) * NC + c) * CH;
  const size_t rowbase = (size_t)b * L_ + c * CH;
  if (t < 256) acs_s[t] = Acs[acsb + t];
  const size_t sb = (((size_t)b * NC + c) * NH + h) * (size_t)(HD * DS);
#pragma unroll
  for (int i = 0; i < 2; ++i) {
    int ci = i * 512 + t; int p = ci >> 4, nk = ci & 15;
    uint4 v = *(const uint4*)&st16[sb + (size_t)p * DS + nk * 8];
    *(uint4*)&pool[p * 136 + nk * 8] = v;
  }
  __syncthreads();
  bf16x8 ca[2][4];
#pragma unroll
  for (int mt = 0; mt < 2; ++mt)
#pragma unroll
    for (int kk = 0; kk < 4; ++kk)
      ca[mt][kk] = *(const bf16x8*)&xbc[(rowbase + w * 32 + mt * 16 + fr) * CONVD +
                                        DI + DS + kk * 32 + oct * 8];
  f32x4 acc_y[2][4];
#pragma unroll
  for (int mt = 0; mt < 2; ++mt)
#pragma unroll
    for (int pp4 = 0; pp4 < 4; ++pp4) acc_y[mt][pp4] = (f32x4){0.f, 0.f, 0.f, 0.f};

  {
    float eL0 = __expf(acs_s[w * 32 + fr]);
    float eL1 = __expf(acs_s[w * 32 + 16 + fr]);
    __builtin_amdgcn_s_setprio(1);
#pragma unroll
    for (int kk = 0; kk < 4; ++kk) {
      bf16x8 c0 = scale8(ca[0][kk], eL0);
      bf16x8 c1 = scale8(ca[1][kk], eL1);
#pragma unroll
      for (int pp4 = 0; pp4 < 4; ++pp4) {
        bf16x8 sf = *(const bf16x8*)&pool[(pp4 * 16 + fr) * 136 + kk * 32 + oct * 8];
        acc_y[0][pp4] = __builtin_amdgcn_mfma_f32_16x16x32_bf16(c0, sf, acc_y[0][pp4], 0, 0, 0);
        acc_y[1][pp4] = __builtin_amdgcn_mfma_f32_16x16x32_bf16(c1, sf, acc_y[1][pp4], 0, 0, 0);
      }
    }
    __builtin_amdgcn_s_setprio(0);
  }

  const int stmax = w >> 1, delta = (w & 1) << 5;
  for (int st = 0; st < 4; ++st) {
    __syncthreads();
#pragma unroll
    for (int i = 0; i < 2; ++i) {
      int ci = i * 512 + t; int ll = ci >> 4, ck = ci & 15;
      uint4 v = *(const uint4*)&xbc[(rowbase + st * 64 + ll) * CONVD + DI + ck * 8];
      *(uint4*)&pool[ll * 128 + ((ck * 8) ^ ((ll & 7) << 3))] = v;
    }
    if (t < 256) {  // Xt[p][s], two s-rows per u32 write
      int lp = t >> 3, pk = t & 7;
      int s0 = lp * 2;
      size_t row0 = rowbase + st * 64 + s0;
      uint4 v0 = *(const uint4*)&xbc[row0 * CONVD + h * HD + pk * 8];
      uint4 v1 = *(const uint4*)&xbc[(row0 + 1) * CONVD + h * HD + pk * 8];
      float d0 = dtp[row0 * NH + h];
      float d1 = dtp[(row0 + 1) * NH + h];
      float o0[8], o1[8];
      unpack8(v0, o0); unpack8(v1, o1);
#pragma unroll
      for (int qq = 0; qq < 8; ++qq) {
        int r = pk * 8 + qq;
        u32 val = (u32)f2us(o0[qq] * d0) | ((u32)f2us(o1[qq] * d1) << 16);
        *(u32*)&pool[XOFF + r * SP + ((((s0 >> 3) ^ (r >> 3)) & 7) << 3) + (s0 & 7)] = val;
      }
    }
    __syncthreads();
    if (st > stmax) continue;
    const bool diag = (st == stmax);
#pragma unroll
    for (int ss4 = 0; ss4 < 4; ++ss4) {
      bf16x8 bbf[4];
#pragma unroll
      for (int kk = 0; kk < 4; ++kk)
        bbf[kk] = *(const bf16x8*)&pool[(ss4 * 16 + fr) * 128 +
                                        ((kk * 32 + oct * 8) ^ ((fr & 7) << 3))];
      int s_in = ss4 * 16 + fr;
      float aS = acs_s[st * 64 + s_in];
#pragma unroll
      for (int mt = 0; mt < 2; ++mt) {
        f32x4 sacc = (f32x4){0.f, 0.f, 0.f, 0.f};
        __builtin_amdgcn_s_setprio(1);
#pragma unroll
        for (int kk = 0; kk < 4; ++kk)
          sacc = __builtin_amdgcn_mfma_f32_16x16x32_bf16(ca[mt][kk], bbf[kk], sacc, 0, 0, 0);
        __builtin_amdgcn_s_setprio(0);
#pragma unroll
        for (int i = 0; i < 4; ++i) {
          int r = mt * 16 + oct * 4 + i;
          float aL = acs_s[w * 32 + r];
          float wgt = (!diag || (s_in <= r + delta)) ? __expf(aL - aS) : 0.0f;
          pool[POFF + w * 2304 + r * SP + s_in] = f2us(sacc[i] * wgt);
        }
      }
    }
    bf16x8 pa[2][2];
#pragma unroll
    for (int mt = 0; mt < 2; ++mt)
#pragma unroll
      for (int k2 = 0; k2 < 2; ++k2)
        pa[mt][k2] = *(const bf16x8*)&pool[POFF + w * 2304 + (mt * 16 + fr) * SP +
                                           k2 * 32 + oct * 8];
    __builtin_amdgcn_s_setprio(1);
#pragma unroll
    for (int pp4 = 0; pp4 < 4; ++pp4) {
      int rx = pp4 * 16 + fr, xg = rx >> 3;
      bf16x8 xb0 = *(const bf16x8*)&pool[XOFF + rx * SP + (((oct) ^ xg) & 7) * 8];
      bf16x8 xb1 = *(const bf16x8*)&pool[XOFF + rx * SP + (((4 + oct) ^ xg) & 7) * 8];
#pragma unroll
      for (int mt = 0; mt < 2; ++mt) {
        acc_y[mt][pp4] = __builtin_amdgcn_mfma_f32_16x16x32_bf16(pa[mt][0], xb0, acc_y[mt][pp4], 0, 0, 0);
        acc_y[mt][pp4] = __builtin_amdgcn_mfma_f32_16x16x32_bf16(pa[mt][1], xb1, acc_y[mt][pp4], 0, 0, 0);
      }
    }
    __builtin_amdgcn_s_setprio(0);
  }

  const float Dh = Dvec[h];
#pragma unroll
  for (int mt = 0; mt < 2; ++mt)
#pragma unroll
    for (int i = 0; i < 4; ++i) {
      size_t row = rowbase + w * 32 + mt * 16 + oct * 4 + i;
#pragma unroll
      for (int pp4 = 0; pp4 < 4; ++pp4) {
        int col = h * HD + pp4 * 16 + fr;
        float xs = us2f(xbc[row * CONVD + col]);
        y[row * DI + col] = f2us(acc_y[mt][pp4][i] + Dh * xs);
      }
    }
}

// ---- gated RMSNorm in place on y (bf16) -------------------------------------
__global__ __launch_bounds__(256) void gnorm_k(const u16* __restrict__ zb,
                                               const float* __restrict__ nw,
                                               u16* __restrict__ y) {
  const int row = blockIdx.x, t = threadIdx.x;
  const u16* zr = zb + (size_t)row * DI;
  u16* yr = y + (size_t)row * DI;
  uint4 zv = *(const uint4*)&zr[t * 8];
  uint4 yv = *(const uint4*)&yr[t * 8];
  float uz[8], uy[8];
  unpack8(zv, uz); unpack8(yv, uy);
  float u[8], ssum = 0.0f;
#pragma unroll
  for (int j = 0; j < 8; ++j) { u[j] = uy[j] * silu_(uz[j]); ssum += u[j] * u[j]; }
#pragma unroll
  for (int off = 32; off >= 1; off >>= 1) ssum += __shfl_xor(ssum, off, 64);
  __shared__ float red[4];
  if ((t & 63) == 0) red[t >> 6] = ssum;
  __syncthreads();
  float sc = rsqrtf((red[0] + red[1] + red[2] + red[3]) * (1.0f / DI) + 1e-5f);
  float4 w0 = *(const float4*)&nw[t * 8];
  float4 w1 = *(const float4*)&nw[t * 8 + 4];
  float o0 = u[0] * sc * w0.x, o1 = u[1] * sc * w0.y, o2 = u[2] * sc * w0.z, o3 = u[3] * sc * w0.w;
  float o4 = u[4] * sc * w1.x, o5 = u[5] * sc * w1.y, o6 = u[6] * sc * w1.z, o7 = u[7] * sc * w1.w;
  uint4 ov;
  ov.x = (u32)f2us(o0) | ((u32)f2us(o1) << 16);
  ov.y = (u32)f2us(o2) | ((u32)f2us(o3) << 16);
  ov.z = (u32)f2us(o4) | ((u32)f2us(o5) << 16);
  ov.w = (u32)f2us(o6) | ((u32)f2us(o7) << 16);
  *(uint4*)&yr[t * 8] = ov;
}

extern "C" void kernel_launch(void* const* d_in, const int* in_sizes, int n_in,
                              void* d_out, int out_size, void* d_ws, size_t ws_size,
                              hipStream_t stream) {
  const float* x      = (const float*)d_in[0];
  const float* W_in   = (const float*)d_in[1];
  const float* conv_w = (const float*)d_in[2];
  const float* conv_b = (const float*)d_in[3];
  const float* dt_b   = (const float*)d_in[4];
  const float* A_log  = (const float*)d_in[5];
  const float* Dvec   = (const float*)d_in[6];
  const float* norm_w = (const float*)d_in[7];
  const float* W_out  = (const float*)d_in[8];
  float* out = (float*)d_out;

  u16* zb       = (u16*)d_ws;                              // 33.55 MB
  u16* xbc      = zb + (size_t)B_ * L_ * DI;               // 37.75 MB
  float* dtp    = (float*)(xbc + (size_t)B_ * L_ * CONVD); // 1.05 MB
  float* Acs    = dtp + (size_t)B_ * L_ * NH;              // 1.05 MB
  u16* stregion = (u16*)(Acs + (size_t)B_ * NH * L_);      // 33.55 MB region
  u16* uni      = stregion + (size_t)B_ * NC * NH * HD * DS * 2;  // 37.75 MB
  u16* xraw = uni;
  u16* y    = uni;

  u16* xb16     = stregion;
  u16* wint     = stregion + (size_t)B_ * L_ * DM;
  u16* states16 = stregion;
  u16* woutt    = stregion;

  const int Mrows = B_ * L_;

  dt_gemm_k<<<Mrows / 8, 256, 0, stream>>>(x, W_in, dt_b, dtp, xb16);
  cvt_t_k<<<dim3(NGEMM / 64, DM / 64), 256, 0, stream>>>(W_in, wint, DPROJ, DM);

  const int nwg_in = (Mrows / 256) * (NGEMM / 128);   // 32*34 = 1088
  gemm_in_k<<<nwg_in, 512, 0, stream>>>(xb16, wint, zb, xraw, nwg_in);

  conv_silu_k<<<(Mrows * (CONVD / 8)) / 256, 256, 0, stream>>>(xraw, conv_w, conv_b, xbc);
  acs_k<<<(B_ * NH * NC) / 4, 256, 0, stream>>>(dtp, A_log, Acs);
  states_k<<<B_ * NC * NH, 256, 0, stream>>>(xbc, dtp, Acs, states16);
  scan_k<<<B_ * NH * 16, 256, 0, stream>>>(states16, Acs);
  ssd_out_k<<<B_ * NC * NH, 512, 0, stream>>>(xbc, dtp, Acs, states16, Dvec, y);
  gnorm_k<<<Mrows, 256, 0, stream>>>(zb, norm_w, y);

  cvt_t_k<<<dim3(DM / 64, DI / 64), 256, 0, stream>>>(W_out, woutt, DM, DI);
  const int nwg_out = (Mrows / 128) * (DM / 128);     // 512
  gemm_bf16_k<DI, DM / 128><<<nwg_out, 256, 0, stream>>>(y, woutt, out, nwg_out);
}

// Round 12
// 339.638 us; speedup vs baseline: 1.0805x; 1.0185x over previous
//
#include <hip/hip_runtime.h>
#include <math.h>

#define B_ 2
#define L_ 4096
#define DM 1024
#define DI 2048
#define HD 64
#define NH 32
#define DS 128
#define CH 256
#define NC 16
#define DPROJ 4384   // 2*DI + 2*DS + NH
#define CONVD 2304   // DI + 2*DS
#define NGEMM 4352   // z + xBC columns (dt handled separately)

typedef unsigned short u16;
typedef unsigned int u32;
typedef __attribute__((ext_vector_type(8))) short bf16x8;
typedef __attribute__((ext_vector_type(4))) float f32x4;

__device__ __forceinline__ float silu_(float x) { return x / (1.0f + __expf(-x)); }
__device__ __forceinline__ float us2f(u16 u) {
  union { u32 i; float f; } c; c.i = ((u32)u) << 16; return c.f;
}
__device__ __forceinline__ u16 f2us(float f) {
  union { float f; u32 i; } c; c.f = f;
  u32 i = c.i;
  return (u16)((i + 0x7FFFu + ((i >> 16) & 1u)) >> 16);  // round-nearest-even
}
__device__ __forceinline__ void unpack8(uint4 v, float* o) {
  o[0] = us2f(v.x & 0xffffu); o[1] = us2f(v.x >> 16);
  o[2] = us2f(v.y & 0xffffu); o[3] = us2f(v.y >> 16);
  o[4] = us2f(v.z & 0xffffu); o[5] = us2f(v.z >> 16);
  o[6] = us2f(v.w & 0xffffu); o[7] = us2f(v.w >> 16);
}
__device__ __forceinline__ void unpk16(uint4 v, u16* o) {
  o[0] = (u16)(v.x & 0xffffu); o[1] = (u16)(v.x >> 16);
  o[2] = (u16)(v.y & 0xffffu); o[3] = (u16)(v.y >> 16);
  o[4] = (u16)(v.z & 0xffffu); o[5] = (u16)(v.z >> 16);
  o[6] = (u16)(v.w & 0xffffu); o[7] = (u16)(v.w >> 16);
}
__device__ __forceinline__ bf16x8 scale8(bf16x8 a, float s) {
  bf16x8 r;
#pragma unroll
  for (int j = 0; j < 8; ++j) r[j] = (short)f2us(us2f((u16)a[j]) * s);
  return r;
}
__device__ __forceinline__ void gload16(const u16* g, u16* l) {
  __builtin_amdgcn_global_load_lds(
      (const __attribute__((address_space(1))) void*)g,
      (__attribute__((address_space(3))) void*)l, 16, 0, 0);
}

// ---- transpose + convert: Wt[n][k] = (bf16) W[k][n] -------------------------
__global__ __launch_bounds__(256) void cvt_t_k(const float* __restrict__ W,
                                               u16* __restrict__ Wt,
                                               int ldW, int ldT) {
  __shared__ float tile[64][65];
  const int t = threadIdx.x;
  const int n0 = blockIdx.x * 64, k0 = blockIdx.y * 64;
#pragma unroll
  for (int i = 0; i < 16; ++i) {
    int j = i * 256 + t;
    int kk = j >> 6, nn = j & 63;
    tile[kk][nn] = W[(size_t)(k0 + kk) * ldW + n0 + nn];
  }
  __syncthreads();
#pragma unroll
  for (int i = 0; i < 16; ++i) {
    int j = i * 256 + t;
    int nn = j >> 6, kk = j & 63;
    Wt[(size_t)(n0 + nn) * ldT + k0 + kk] = f2us(tile[kk][nn]);
  }
}

// ---- transpose + convert + fold norm_w: Wt[n][k] = bf16(W[k][n] * nw[k]) ----
__global__ __launch_bounds__(256) void cvt_tw_k(const float* __restrict__ W,
                                                const float* __restrict__ nw,
                                                u16* __restrict__ Wt,
                                                int ldW, int ldT) {
  __shared__ float tile[64][65];
  const int t = threadIdx.x;
  const int n0 = blockIdx.x * 64, k0 = blockIdx.y * 64;
#pragma unroll
  for (int i = 0; i < 16; ++i) {
    int j = i * 256 + t;
    int kk = j >> 6, nn = j & 63;
    tile[kk][nn] = W[(size_t)(k0 + kk) * ldW + n0 + nn] * nw[k0 + kk];
  }
  __syncthreads();
#pragma unroll
  for (int i = 0; i < 16; ++i) {
    int j = i * 256 + t;
    int nn = j >> 6, kk = j & 63;
    Wt[(size_t)(n0 + nn) * ldT + k0 + kk] = f2us(tile[kk][nn]);
  }
}

// ==== 256x128 bf16 MFMA GEMM (in-proj) ======================================
__global__ __launch_bounds__(512, 4) void gemm_in_k(const u16* __restrict__ A,
                                                    const u16* __restrict__ Bt,
                                                    u16* __restrict__ zb,
                                                    u16* __restrict__ xraw,
                                                    int nwg) {
  __shared__ u16 pool[24576];   // Al[256][64] @0, Bl[128][64] @16384
  u16* Al = pool;
  u16* Bl = pool + 16384;
  const int t = threadIdx.x;
  const int w = t >> 6, lane = t & 63;
  const int fr = lane & 15, oct = lane >> 4;
  const int wm = w >> 1, wn = w & 1;
  const int q = nwg >> 3;
  const int wg = (blockIdx.x & 7) * q + (blockIdx.x >> 3);
  const int bm = wg / (NGEMM / 128), bn = wg % (NGEMM / 128);
  const int m0 = bm * 256, n0 = bn * 128;
  const int lr = lane >> 3, ls = lane & 7;
  const int gslot = (ls ^ lr) * 8;   // XOR involution: LDS[r][s] = G[r][s^(r&7)]

  f32x4 acc[4][4];
#pragma unroll
  for (int mm = 0; mm < 4; ++mm)
#pragma unroll
    for (int nn = 0; nn < 4; ++nn) acc[mm][nn] = (f32x4){0.f, 0.f, 0.f, 0.f};

  for (int k0 = 0; k0 < DM; k0 += 64) {
    if (k0) __syncthreads();
#pragma unroll
    for (int i = 0; i < 4; ++i) {
      const int rowA = w * 32 + i * 8;
      gload16(&A[(size_t)(m0 + rowA + lr) * DM + k0 + gslot], &Al[rowA * 64]);
    }
#pragma unroll
    for (int i = 0; i < 2; ++i) {
      const int rowB = w * 16 + i * 8;
      gload16(&Bt[(size_t)(n0 + rowB + lr) * DM + k0 + gslot], &Bl[rowB * 64]);
    }
    __syncthreads();
#pragma unroll
    for (int kk = 0; kk < 2; ++kk) {
      bf16x8 af[4], bfr[4];
#pragma unroll
      for (int mm = 0; mm < 4; ++mm)
        af[mm] = *(const bf16x8*)&Al[(wm * 64 + mm * 16 + fr) * 64 +
                                     (((kk * 4 + oct) ^ (fr & 7)) * 8)];
#pragma unroll
      for (int nn = 0; nn < 4; ++nn)
        bfr[nn] = *(const bf16x8*)&Bl[(wn * 64 + nn * 16 + fr) * 64 +
                                      (((kk * 4 + oct) ^ (fr & 7)) * 8)];
      __builtin_amdgcn_s_setprio(1);
#pragma unroll
      for (int mm = 0; mm < 4; ++mm)
#pragma unroll
        for (int nn = 0; nn < 4; ++nn)
          acc[mm][nn] = __builtin_amdgcn_mfma_f32_16x16x32_bf16(af[mm], bfr[nn],
                                                                acc[mm][nn], 0, 0, 0);
      __builtin_amdgcn_s_setprio(0);
    }
  }

  const bool isz = (n0 < DI);
  u16* Oh = pool;
#pragma unroll
  for (int P = 0; P < 4; ++P) {
    __syncthreads();
    if (wm == P) {
#pragma unroll
      for (int mm = 0; mm < 4; ++mm)
#pragma unroll
        for (int i = 0; i < 4; ++i) {
          int rloc = mm * 16 + oct * 4 + i;
#pragma unroll
          for (int nn = 0; nn < 4; ++nn)
            Oh[rloc * 136 + wn * 64 + nn * 16 + fr] = f2us(acc[mm][nn][i]);
        }
    }
    __syncthreads();
#pragma unroll
    for (int p = 0; p < 2; ++p) {
      int e = p * 512 + t;
      int row = e >> 4, cs = (e & 15) * 8;
      uint4 v = *(const uint4*)&Oh[row * 136 + cs];
      size_t grow = m0 + P * 64 + row;
      int col = n0 + cs;
      if (isz) *(uint4*)&zb[grow * DI + col] = v;
      else     *(uint4*)&xraw[grow * CONVD + (col - DI)] = v;
    }
  }
}

// ---- bf16 MFMA GEMM 128x128 (out-proj, fp32 out, RMS row-scale epilogue) ----
template <int KDIM, int NTN>
__global__ __launch_bounds__(256) void gemm_bf16_k(const u16* __restrict__ A,
                                                   const u16* __restrict__ Bt,
                                                   const float* __restrict__ rowsum,
                                                   float* __restrict__ outf,
                                                   int nwg) {
  __shared__ u16 pool[17408];
  u16* Al = pool;
  u16* Bl = pool + 8192;
  const int t = threadIdx.x;
  const int wv = t >> 6, lane = t & 63;
  const int fr = lane & 15, oct = lane >> 4;
  const int wr = wv >> 1, wc = wv & 1;
  const int q = nwg >> 3;
  const int wg = (blockIdx.x & 7) * q + (blockIdx.x >> 3);
  const int bm = wg / NTN, bn = wg % NTN;
  const int m0 = bm * 128, n0 = bn * 128;

  const int lr = lane >> 3, ls = lane & 7;
  const int gslot = (ls ^ lr) * 8;

  f32x4 acc[4][4];
#pragma unroll
  for (int mm = 0; mm < 4; ++mm)
#pragma unroll
    for (int nn = 0; nn < 4; ++nn) acc[mm][nn] = (f32x4){0.f, 0.f, 0.f, 0.f};

  for (int k0 = 0; k0 < KDIM; k0 += 64) {
    if (k0) __syncthreads();
#pragma unroll
    for (int i = 0; i < 4; ++i) {
      const int rowA = wv * 32 + i * 8;
      gload16(&A[(size_t)(m0 + rowA + lr) * KDIM + k0 + gslot], &Al[rowA * 64]);
      gload16(&Bt[(size_t)(n0 + rowA + lr) * KDIM + k0 + gslot], &Bl[rowA * 64]);
    }
    __syncthreads();
#pragma unroll
    for (int kk = 0; kk < 2; ++kk) {
      bf16x8 af[4], bfr[4];
#pragma unroll
      for (int mm = 0; mm < 4; ++mm)
        af[mm] = *(const bf16x8*)&Al[(wr * 64 + mm * 16 + fr) * 64 +
                                     (((kk * 4 + oct) ^ (fr & 7)) * 8)];
#pragma unroll
      for (int nn = 0; nn < 4; ++nn)
        bfr[nn] = *(const bf16x8*)&Bl[(wc * 64 + nn * 16 + fr) * 64 +
                                      (((kk * 4 + oct) ^ (fr & 7)) * 8)];
#pragma unroll
      for (int mm = 0; mm < 4; ++mm)
#pragma unroll
        for (int nn = 0; nn < 4; ++nn)
          acc[mm][nn] = __builtin_amdgcn_mfma_f32_16x16x32_bf16(af[mm], bfr[nn],
                                                                acc[mm][nn], 0, 0, 0);
    }
  }

#pragma unroll
  for (int P = 0; P < 2; ++P) {
    __syncthreads();
    float* Of = (float*)pool;  // [64][132]
    if (wr == P) {
#pragma unroll
      for (int mm = 0; mm < 4; ++mm)
#pragma unroll
        for (int i = 0; i < 4; ++i) {
          int rloc = mm * 16 + oct * 4 + i;
#pragma unroll
          for (int nn = 0; nn < 4; ++nn)
            Of[rloc * 132 + wc * 64 + nn * 16 + fr] = acc[mm][nn][i];
        }
    }
    __syncthreads();
#pragma unroll
    for (int p = 0; p < 8; ++p) {
      int e = p * 256 + t;
      int row = e >> 5, c4 = (e & 31) * 4;
      size_t grow = m0 + P * 64 + row;
      float s = rsqrtf(rowsum[grow] * (1.0f / DI) + 1e-5f);
      float4 v = *(const float4*)&Of[row * 132 + c4];
      v.x *= s; v.y *= s; v.z *= s; v.w *= s;
      *(float4*)&outf[grow * DM + n0 + c4] = v;
    }
  }
}

// ---- rowsum reduce: rowsum[row] = sum_h psum[row][h] ------------------------
__global__ __launch_bounds__(256) void rowsum_k(const float* __restrict__ psum,
                                                float* __restrict__ rowsum) {
  int row = blockIdx.x * 256 + threadIdx.x;
  const float4* p = (const float4*)&psum[(size_t)row * 32];
  float s = 0.0f;
#pragma unroll
  for (int i = 0; i < 8; ++i) {
    float4 v = p[i];
    s += (v.x + v.y) + (v.z + v.w);
  }
  rowsum[row] = s;
}

// ---- dt (fp32 exact) + x->bf16 fused ----------------------------------------
__global__ __launch_bounds__(256) void dt_gemm_k(const float* __restrict__ x,
                                                 const float* __restrict__ W,
                                                 const float* __restrict__ dtb,
                                                 float* __restrict__ dtp,
                                                 u16* __restrict__ xb16) {
  __shared__ float xs[8 * 1024];
  const int t = threadIdx.x;
  const int row0 = blockIdx.x * 8;
#pragma unroll
  for (int i = 0; i < 8; ++i) {
    int j4 = i * 256 + t;
    float4 v = *(const float4*)&x[(size_t)row0 * DM + j4 * 4];
    *(float4*)&xs[j4 * 4] = v;
    u32 lo = (u32)f2us(v.x) | ((u32)f2us(v.y) << 16);
    u32 hi = (u32)f2us(v.z) | ((u32)f2us(v.w) << 16);
    *(uint2*)&xb16[(size_t)row0 * DM + j4 * 4] = make_uint2(lo, hi);
  }
  __syncthreads();
  const int r = t >> 5, h = t & 31;
  float a0 = 0.f, a1 = 0.f, a2 = 0.f, a3 = 0.f;
  const float* wcol = W + (DI + CONVD) + h;
  const float* xr = &xs[r * 1024];
  for (int k = 0; k < 1024; k += 4) {
    float4 xv = *(const float4*)&xr[k];
    a0 += xv.x * wcol[(size_t)(k + 0) * DPROJ];
    a1 += xv.y * wcol[(size_t)(k + 1) * DPROJ];
    a2 += xv.z * wcol[(size_t)(k + 2) * DPROJ];
    a3 += xv.w * wcol[(size_t)(k + 3) * DPROJ];
  }
  float v = (a0 + a1) + (a2 + a3) + dtb[h];
  dtp[(size_t)(row0 + r) * NH + h] = (v > 20.0f) ? v : log1pf(__expf(v));
}

// ---- causal depthwise conv(4) + SiLU ----------------------------------------
__global__ __launch_bounds__(256) void conv_silu_k(const u16* __restrict__ xraw,
                                                   const float* __restrict__ cw,
                                                   const float* __restrict__ cb,
                                                   u16* __restrict__ xbc) {
  int idx = blockIdx.x * 256 + threadIdx.x;
  int ch8 = idx % (CONVD / 8);
  int bl = idx / (CONVD / 8);
  int l = bl & (L_ - 1);
  int ch = ch8 * 8;
  const u16* src = xraw + (size_t)bl * CONVD + ch;
  float a[8], o[8];
#pragma unroll
  for (int qq = 0; qq < 8; ++qq) a[qq] = cb[ch + qq];
  float w0[8], w1[8], w2[8], w3[8];
#pragma unroll
  for (int qq = 0; qq < 8; ++qq) {
    float4 w = *(const float4*)&cw[(ch + qq) * 4];
    w0[qq] = w.x; w1[qq] = w.y; w2[qq] = w.z; w3[qq] = w.w;
  }
  if (l >= 3) {
    uint4 v = *(const uint4*)&src[-3 * CONVD]; unpack8(v, o);
#pragma unroll
    for (int qq = 0; qq < 8; ++qq) a[qq] += o[qq] * w0[qq];
  }
  if (l >= 2) {
    uint4 v = *(const uint4*)&src[-2 * CONVD]; unpack8(v, o);
#pragma unroll
    for (int qq = 0; qq < 8; ++qq) a[qq] += o[qq] * w1[qq];
  }
  if (l >= 1) {
    uint4 v = *(const uint4*)&src[-CONVD]; unpack8(v, o);
#pragma unroll
    for (int qq = 0; qq < 8; ++qq) a[qq] += o[qq] * w2[qq];
  }
  {
    uint4 v = *(const uint4*)&src[0]; unpack8(v, o);
#pragma unroll
    for (int qq = 0; qq < 8; ++qq) a[qq] += o[qq] * w3[qq];
  }
  uint4 ov;
  ov.x = (u32)f2us(silu_(a[0])) | ((u32)f2us(silu_(a[1])) << 16);
  ov.y = (u32)f2us(silu_(a[2])) | ((u32)f2us(silu_(a[3])) << 16);
  ov.z = (u32)f2us(silu_(a[4])) | ((u32)f2us(silu_(a[5])) << 16);
  ov.w = (u32)f2us(silu_(a[6])) | ((u32)f2us(silu_(a[7])) << 16);
  *(uint4*)&xbc[(size_t)bl * CONVD + ch] = ov;
}

// ---- per-(b,h,c) cumsum of dt*A ---------------------------------------------
__global__ __launch_bounds__(256) void acs_k(const float* __restrict__ dtp,
                                             const float* __restrict__ A_log,
                                             float* __restrict__ Acs) {
  const int t = threadIdx.x;
  const int lane = t & 63, wv = t >> 6;
  const int idx = blockIdx.x * 4 + wv;
  const int h = (idx >> 4) & (NH - 1);
  const int c = idx & (NC - 1);
  const int b = idx >> 9;
  const float Ah = -__expf(A_log[h]);
  const size_t base = ((size_t)b * L_ + c * CH + lane * 4) * NH + h;
  float v0 = dtp[base] * Ah;
  float v1 = dtp[base + NH] * Ah;
  float v2 = dtp[base + 2 * NH] * Ah;
  float v3 = dtp[base + 3 * NH] * Ah;
  float c1 = v0 + v1, c2 = c1 + v2, c3 = c2 + v3;
  float tot = c3;
#pragma unroll
  for (int off = 1; off < 64; off <<= 1) {
    float p = __shfl_up(tot, off, 64);
    if (lane >= off) tot += p;
  }
  float excl = tot - c3;
  float4 ov = make_float4(excl + v0, excl + c1, excl + c2, excl + c3);
  *(float4*)&Acs[(size_t)idx * CH + lane * 4] = ov;
}

// ---- chunk end-states via MFMA -> bf16 --------------------------------------
#define SLP 72
__global__ __launch_bounds__(256) void states_k(const u16* __restrict__ xbc,
                                                const float* __restrict__ dtp,
                                                const float* __restrict__ Acs,
                                                u16* __restrict__ st16) {
  __shared__ u16 BtT[128 * SLP];
  __shared__ u16 XtT[64 * SLP];
  const int t = threadIdx.x;
  const int wv = t >> 6, lane = t & 63;
  const int fr = lane & 15, oct = lane >> 4;
  const int sw = (blockIdx.x & 7) * 128 + (blockIdx.x >> 3);  // XCD swizzle
  const int h = sw & 31, c = (sw >> 5) & 15, b = sw >> 9;
  const size_t acsb = (((size_t)b * NH + h) * NC + c) * CH;
  const float acs_last = Acs[acsb + (CH - 1)];
  const size_t rowbase = (size_t)b * L_ + c * CH;

  f32x4 acc[2][4];
#pragma unroll
  for (int mt = 0; mt < 2; ++mt)
#pragma unroll
    for (int pt = 0; pt < 4; ++pt) acc[mt][pt] = (f32x4){0.f, 0.f, 0.f, 0.f};

  for (int lt = 0; lt < 4; ++lt) {
    __syncthreads();
#pragma unroll
    for (int i = 0; i < 2; ++i) {
      int ci = i * 256 + t;
      int lp = ci >> 4, nk = ci & 15;
      int l0 = lp * 2;
      const u16* srcp = &xbc[(rowbase + lt * 64 + l0) * CONVD + DI + nk * 8];
      uint4 v0 = *(const uint4*)srcp;
      uint4 v1 = *(const uint4*)(srcp + CONVD);
      u16 a0[8], a1[8];
      unpk16(v0, a0); unpk16(v1, a1);
#pragma unroll
      for (int qq = 0; qq < 8; ++qq) {
        int r = nk * 8 + qq;
        u32 val = (u32)a0[qq] | ((u32)a1[qq] << 16);
        *(u32*)&BtT[r * SLP + ((((l0 >> 3) ^ (r >> 3)) & 7) << 3) + (l0 & 7)] = val;
      }
    }
    {
      int lp = t >> 3, pk = t & 7;
      int l0 = lp * 2;
      size_t row0 = rowbase + lt * 64 + l0;
      uint4 v0 = *(const uint4*)&xbc[row0 * CONVD + h * HD + pk * 8];
      uint4 v1 = *(const uint4*)&xbc[(row0 + 1) * CONVD + h * HD + pk * 8];
      float d0 = dtp[row0 * NH + h] * __expf(acs_last - Acs[acsb + lt * 64 + l0]);
      float d1 = dtp[(row0 + 1) * NH + h] * __expf(acs_last - Acs[acsb + lt * 64 + l0 + 1]);
      float o0[8], o1[8];
      unpack8(v0, o0); unpack8(v1, o1);
#pragma unroll
      for (int qq = 0; qq < 8; ++qq) {
        int r = pk * 8 + qq;
        u32 val = (u32)f2us(o0[qq] * d0) | ((u32)f2us(o1[qq] * d1) << 16);
        *(u32*)&XtT[r * SLP + ((((l0 >> 3) ^ (r >> 3)) & 7) << 3) + (l0 & 7)] = val;
      }
    }
    __syncthreads();
    __builtin_amdgcn_s_setprio(1);
#pragma unroll
    for (int ks = 0; ks < 2; ++ks) {
      bf16x8 afr[2], bfr[4];
#pragma unroll
      for (int mt = 0; mt < 2; ++mt) {
        int r = wv * 32 + mt * 16 + fr;
        afr[mt] = *(const bf16x8*)&BtT[r * SLP + ((((ks * 4 + oct) ^ (r >> 3)) & 7) << 3)];
      }
#pragma unroll
      for (int pt = 0; pt < 4; ++pt) {
        int r = pt * 16 + fr;
        bfr[pt] = *(const bf16x8*)&XtT[r * SLP + ((((ks * 4 + oct) ^ (r >> 3)) & 7) << 3)];
      }
#pragma unroll
      for (int mt = 0; mt < 2; ++mt)
#pragma unroll
        for (int pt = 0; pt < 4; ++pt)
          acc[mt][pt] = __builtin_amdgcn_mfma_f32_16x16x32_bf16(afr[mt], bfr[pt],
                                                                acc[mt][pt], 0, 0, 0);
    }
    __builtin_amdgcn_s_setprio(0);
  }
  size_t sbase = (((size_t)b * NC + c) * NH + h) * (size_t)(HD * DS);
#pragma unroll
  for (int mt = 0; mt < 2; ++mt)
#pragma unroll
    for (int pt = 0; pt < 4; ++pt) {
      int p = pt * 16 + fr;
      int n0 = wv * 32 + mt * 16 + oct * 4;
      u32 lo = (u32)f2us(acc[mt][pt][0]) | ((u32)f2us(acc[mt][pt][1]) << 16);
      u32 hi = (u32)f2us(acc[mt][pt][2]) | ((u32)f2us(acc[mt][pt][3]) << 16);
      *(uint2*)&st16[sbase + (size_t)p * DS + n0] = make_uint2(lo, hi);
    }
}

// ---- inter-chunk scan (bf16 states, fp32 carry) -----------------------------
__global__ __launch_bounds__(256) void scan_k(u16* __restrict__ st16,
                                              const float* __restrict__ Acs) {
  const int t = threadIdx.x;
  const int seg = blockIdx.x & 15;
  const int bh = blockIdx.x >> 4;
  const int h = bh & 31, b = bh >> 5;
  const int e2 = seg * 256 + t;
  const size_t acssb = ((size_t)b * NH + h) * NC * CH;
  float run0 = 0.0f, run1 = 0.0f;
#pragma unroll
  for (int c = 0; c < NC; ++c) {
    float dAl = __expf(Acs[acssb + (size_t)c * CH + (CH - 1)]);
    size_t e = (((size_t)b * NC + c) * NH + h) * (size_t)(HD * DS) + e2 * 2;
    u32 v = *(const u32*)&st16[e];
    float s0 = us2f((u16)(v & 0xffffu)), s1 = us2f((u16)(v >> 16));
    *(u32*)&st16[e] = (u32)f2us(run0) | ((u32)f2us(run1) << 16);
    run0 = fmaf(dAl, run0, s0);
    run1 = fmaf(dAl, run1, s1);
  }
}

// ---- merged SSD + gated-v + partial row-sums --------------------------------
#define SP 72
#define XOFF 8192
#define POFF 12800
__global__ __launch_bounds__(512, 4) void ssd_out_k(const u16* __restrict__ xbc,
                                                    const float* __restrict__ dtp,
                                                    const float* __restrict__ Acs,
                                                    const u16* __restrict__ st16,
                                                    const float* __restrict__ Dvec,
                                                    const u16* __restrict__ zb,
                                                    u16* __restrict__ v_out,
                                                    float* __restrict__ psum) {
  __shared__ u16 pool[31232];
  __shared__ float acs_s[256];
  const int t = threadIdx.x;
  const int w = t >> 6, lane = t & 63;
  const int fr = lane & 15, oct = lane >> 4;
  const int sw = (blockIdx.x & 7) * 128 + (blockIdx.x >> 3);  // XCD swizzle
  const int h = sw & 31, c = (sw >> 5) & 15, b = sw >> 9;
  const size_t acsb = (((size_t)b * NH + h) * NC + c) * CH;
  const size_t rowbase = (size_t)b * L_ + c * CH;
  if (t < 256) acs_s[t] = Acs[acsb + t];
  const size_t sb = (((size_t)b * NC + c) * NH + h) * (size_t)(HD * DS);
#pragma unroll
  for (int i = 0; i < 2; ++i) {
    int ci = i * 512 + t; int p = ci >> 4, nk = ci & 15;
    uint4 v = *(const uint4*)&st16[sb + (size_t)p * DS + nk * 8];
    *(uint4*)&pool[p * 136 + nk * 8] = v;
  }
  __syncthreads();
  bf16x8 ca[2][4];
#pragma unroll
  for (int mt = 0; mt < 2; ++mt)
#pragma unroll
    for (int kk = 0; kk < 4; ++kk)
      ca[mt][kk] = *(const bf16x8*)&xbc[(rowbase + w * 32 + mt * 16 + fr) * CONVD +
                                        DI + DS + kk * 32 + oct * 8];
  f32x4 acc_y[2][4];
#pragma unroll
  for (int mt = 0; mt < 2; ++mt)
#pragma unroll
    for (int pp4 = 0; pp4 < 4; ++pp4) acc_y[mt][pp4] = (f32x4){0.f, 0.f, 0.f, 0.f};

  {
    float eL0 = __expf(acs_s[w * 32 + fr]);
    float eL1 = __expf(acs_s[w * 32 + 16 + fr]);
    __builtin_amdgcn_s_setprio(1);
#pragma unroll
    for (int kk = 0; kk < 4; ++kk) {
      bf16x8 c0 = scale8(ca[0][kk], eL0);
      bf16x8 c1 = scale8(ca[1][kk], eL1);
#pragma unroll
      for (int pp4 = 0; pp4 < 4; ++pp4) {
        bf16x8 sf = *(const bf16x8*)&pool[(pp4 * 16 + fr) * 136 + kk * 32 + oct * 8];
        acc_y[0][pp4] = __builtin_amdgcn_mfma_f32_16x16x32_bf16(c0, sf, acc_y[0][pp4], 0, 0, 0);
        acc_y[1][pp4] = __builtin_amdgcn_mfma_f32_16x16x32_bf16(c1, sf, acc_y[1][pp4], 0, 0, 0);
      }
    }
    __builtin_amdgcn_s_setprio(0);
  }

  const int stmax = w >> 1, delta = (w & 1) << 5;
  for (int st = 0; st < 4; ++st) {
    __syncthreads();
#pragma unroll
    for (int i = 0; i < 2; ++i) {
      int ci = i * 512 + t; int ll = ci >> 4, ck = ci & 15;
      uint4 v = *(const uint4*)&xbc[(rowbase + st * 64 + ll) * CONVD + DI + ck * 8];
      *(uint4*)&pool[ll * 128 + ((ck * 8) ^ ((ll & 7) << 3))] = v;
    }
    if (t < 256) {
      int lp = t >> 3, pk = t & 7;
      int s0 = lp * 2;
      size_t row0 = rowbase + st * 64 + s0;
      uint4 v0 = *(const uint4*)&xbc[row0 * CONVD + h * HD + pk * 8];
      uint4 v1 = *(const uint4*)&xbc[(row0 + 1) * CONVD + h * HD + pk * 8];
      float d0 = dtp[row0 * NH + h];
      float d1 = dtp[(row0 + 1) * NH + h];
      float o0[8], o1[8];
      unpack8(v0, o0); unpack8(v1, o1);
#pragma unroll
      for (int qq = 0; qq < 8; ++qq) {
        int r = pk * 8 + qq;
        u32 val = (u32)f2us(o0[qq] * d0) | ((u32)f2us(o1[qq] * d1) << 16);
        *(u32*)&pool[XOFF + r * SP + ((((s0 >> 3) ^ (r >> 3)) & 7) << 3) + (s0 & 7)] = val;
      }
    }
    __syncthreads();
    if (st > stmax) continue;
    const bool diag = (st == stmax);
#pragma unroll
    for (int ss4 = 0; ss4 < 4; ++ss4) {
      bf16x8 bbf[4];
#pragma unroll
      for (int kk = 0; kk < 4; ++kk)
        bbf[kk] = *(const bf16x8*)&pool[(ss4 * 16 + fr) * 128 +
                                        ((kk * 32 + oct * 8) ^ ((fr & 7) << 3))];
      int s_in = ss4 * 16 + fr;
      float aS = acs_s[st * 64 + s_in];
#pragma unroll
      for (int mt = 0; mt < 2; ++mt) {
        f32x4 sacc = (f32x4){0.f, 0.f, 0.f, 0.f};
        __builtin_amdgcn_s_setprio(1);
#pragma unroll
        for (int kk = 0; kk < 4; ++kk)
          sacc = __builtin_amdgcn_mfma_f32_16x16x32_bf16(ca[mt][kk], bbf[kk], sacc, 0, 0, 0);
        __builtin_amdgcn_s_setprio(0);
#pragma unroll
        for (int i = 0; i < 4; ++i) {
          int r = mt * 16 + oct * 4 + i;
          float aL = acs_s[w * 32 + r];
          float wgt = (!diag || (s_in <= r + delta)) ? __expf(aL - aS) : 0.0f;
          pool[POFF + w * 2304 + r * SP + s_in] = f2us(sacc[i] * wgt);
        }
      }
    }
    bf16x8 pa[2][2];
#pragma unroll
    for (int mt = 0; mt < 2; ++mt)
#pragma unroll
      for (int k2 = 0; k2 < 2; ++k2)
        pa[mt][k2] = *(const bf16x8*)&pool[POFF + w * 2304 + (mt * 16 + fr) * SP +
                                           k2 * 32 + oct * 8];
    __builtin_amdgcn_s_setprio(1);
#pragma unroll
    for (int pp4 = 0; pp4 < 4; ++pp4) {
      int rx = pp4 * 16 + fr, xg = rx >> 3;
      bf16x8 xb0 = *(const bf16x8*)&pool[XOFF + rx * SP + (((oct) ^ xg) & 7) * 8];
      bf16x8 xb1 = *(const bf16x8*)&pool[XOFF + rx * SP + (((4 + oct) ^ xg) & 7) * 8];
#pragma unroll
      for (int mt = 0; mt < 2; ++mt) {
        acc_y[mt][pp4] = __builtin_amdgcn_mfma_f32_16x16x32_bf16(pa[mt][0], xb0, acc_y[mt][pp4], 0, 0, 0);
        acc_y[mt][pp4] = __builtin_amdgcn_mfma_f32_16x16x32_bf16(pa[mt][1], xb1, acc_y[mt][pp4], 0, 0, 0);
      }
    }
    __builtin_amdgcn_s_setprio(0);
  }

  // epilogue: v = (Yd + Yo + D*xs) * silu(z); partial row-sums of v^2
  const float Dh = Dvec[h];
  float rs[2][4];
#pragma unroll
  for (int mt = 0; mt < 2; ++mt)
#pragma unroll
    for (int i = 0; i < 4; ++i) {
      size_t row = rowbase + w * 32 + mt * 16 + oct * 4 + i;
      float rsum = 0.0f;
#pragma unroll
      for (int pp4 = 0; pp4 < 4; ++pp4) {
        int col = h * HD + pp4 * 16 + fr;
        float xs = us2f(xbc[row * CONVD + col]);
        float zz = us2f(zb[row * DI + col]);
        float vv = (acc_y[mt][pp4][i] + Dh * xs) * silu_(zz);
        v_out[row * DI + col] = f2us(vv);
        rsum += vv * vv;
      }
      rs[mt][i] = rsum;
    }
#pragma unroll
  for (int mt = 0; mt < 2; ++mt)
#pragma unroll
    for (int i = 0; i < 4; ++i) {
      float s = rs[mt][i];
#pragma unroll
      for (int off = 8; off >= 1; off >>= 1) s += __shfl_xor(s, off, 64);
      if (fr == 0) {
        size_t row = rowbase + w * 32 + mt * 16 + oct * 4 + i;
        psum[row * 32 + h] = s;
      }
    }
}

extern "C" void kernel_launch(void* const* d_in, const int* in_sizes, int n_in,
                              void* d_out, int out_size, void* d_ws, size_t ws_size,
                              hipStream_t stream) {
  const float* x      = (const float*)d_in[0];
  const float* W_in   = (const float*)d_in[1];
  const float* conv_w = (const float*)d_in[2];
  const float* conv_b = (const float*)d_in[3];
  const float* dt_b   = (const float*)d_in[4];
  const float* A_log  = (const float*)d_in[5];
  const float* Dvec   = (const float*)d_in[6];
  const float* norm_w = (const float*)d_in[7];
  const float* W_out  = (const float*)d_in[8];
  float* out = (float*)d_out;

  u16* zb       = (u16*)d_ws;                              // 33.55 MB
  u16* xbc      = zb + (size_t)B_ * L_ * DI;               // 37.75 MB
  float* dtp    = (float*)(xbc + (size_t)B_ * L_ * CONVD); // 1.05 MB
  float* Acs    = dtp + (size_t)B_ * L_ * NH;              // 1.05 MB
  u16* stregion = (u16*)(Acs + (size_t)B_ * NH * L_);      // 33.55 MB region
  u16* uni      = stregion + (size_t)B_ * NC * NH * HD * DS * 2;  // 37.75 MB
  u16* xraw = uni;
  u16* v    = uni;   // v = gated SSD output, aliases xraw

  // stregion timeline: [xb16|wint] -> [states16 | psum | rowsum] -> [woutt | psum | rowsum]
  u16* xb16     = stregion;
  u16* wint     = stregion + (size_t)B_ * L_ * DM;
  u16* states16 = stregion;                                           // 16.78 MB
  float* psum   = (float*)(stregion + (size_t)B_ * NC * NH * HD * DS); // 1 MB
  float* rowsum = psum + (size_t)B_ * L_ * NH;                        // 32 KB
  u16* woutt    = stregion;                                           // 4.19 MB

  const int Mrows = B_ * L_;

  dt_gemm_k<<<Mrows / 8, 256, 0, stream>>>(x, W_in, dt_b, dtp, xb16);
  cvt_t_k<<<dim3(NGEMM / 64, DM / 64), 256, 0, stream>>>(W_in, wint, DPROJ, DM);

  const int nwg_in = (Mrows / 256) * (NGEMM / 128);   // 1088
  gemm_in_k<<<nwg_in, 512, 0, stream>>>(xb16, wint, zb, xraw, nwg_in);

  conv_silu_k<<<(Mrows * (CONVD / 8)) / 256, 256, 0, stream>>>(xraw, conv_w, conv_b, xbc);
  acs_k<<<(B_ * NH * NC) / 4, 256, 0, stream>>>(dtp, A_log, Acs);
  states_k<<<B_ * NC * NH, 256, 0, stream>>>(xbc, dtp, Acs, states16);
  scan_k<<<B_ * NH * 16, 256, 0, stream>>>(states16, Acs);
  ssd_out_k<<<B_ * NC * NH, 512, 0, stream>>>(xbc, dtp, Acs, states16, Dvec,
                                              zb, v, psum);
  rowsum_k<<<Mrows / 256, 256, 0, stream>>>(psum, rowsum);

  cvt_tw_k<<<dim3(DM / 64, DI / 64), 256, 0, stream>>>(W_out, norm_w, woutt, DM, DI);
  const int nwg_out = (Mrows / 128) * (DM / 128);     // 512
  gemm_bf16_k<DI, DM / 128><<<nwg_out, 256, 0, stream>>>(v, woutt, rowsum, out, nwg_out);
}

// Round 13
// 338.132 us; speedup vs baseline: 1.0853x; 1.0045x over previous
//
#include <hip/hip_runtime.h>
#include <math.h>

#define B_ 2
#define L_ 4096
#define DM 1024
#define DI 2048
#define HD 64
#define NH 32
#define DS 128
#define CH 256
#define NC 16
#define DPROJ 4384   // 2*DI + 2*DS + NH
#define CONVD 2304   // DI + 2*DS
#define NGEMM 4352   // z + xBC columns (dt handled separately)

typedef unsigned short u16;
typedef unsigned int u32;
typedef __attribute__((ext_vector_type(8))) short bf16x8;
typedef __attribute__((ext_vector_type(4))) float f32x4;

__device__ __forceinline__ float silu_(float x) { return x / (1.0f + __expf(-x)); }
__device__ __forceinline__ float us2f(u16 u) {
  union { u32 i; float f; } c; c.i = ((u32)u) << 16; return c.f;
}
__device__ __forceinline__ u16 f2us(float f) {
  union { float f; u32 i; } c; c.f = f;
  u32 i = c.i;
  return (u16)((i + 0x7FFFu + ((i >> 16) & 1u)) >> 16);  // round-nearest-even
}
__device__ __forceinline__ void unpack8(uint4 v, float* o) {
  o[0] = us2f(v.x & 0xffffu); o[1] = us2f(v.x >> 16);
  o[2] = us2f(v.y & 0xffffu); o[3] = us2f(v.y >> 16);
  o[4] = us2f(v.z & 0xffffu); o[5] = us2f(v.z >> 16);
  o[6] = us2f(v.w & 0xffffu); o[7] = us2f(v.w >> 16);
}
__device__ __forceinline__ void unpk16(uint4 v, u16* o) {
  o[0] = (u16)(v.x & 0xffffu); o[1] = (u16)(v.x >> 16);
  o[2] = (u16)(v.y & 0xffffu); o[3] = (u16)(v.y >> 16);
  o[4] = (u16)(v.z & 0xffffu); o[5] = (u16)(v.z >> 16);
  o[6] = (u16)(v.w & 0xffffu); o[7] = (u16)(v.w >> 16);
}
__device__ __forceinline__ bf16x8 scale8(bf16x8 a, float s) {
  bf16x8 r;
#pragma unroll
  for (int j = 0; j < 8; ++j) r[j] = (short)f2us(us2f((u16)a[j]) * s);
  return r;
}
__device__ __forceinline__ void gload16(const u16* g, u16* l) {
  __builtin_amdgcn_global_load_lds(
      (const __attribute__((address_space(1))) void*)g,
      (__attribute__((address_space(3))) void*)l, 16, 0, 0);
}

// ==== fused prep: dt(fp32)+x->bf16 | W_in transpose | W_out transpose*nw ====
// grid = 1024 (dt) + 1088 (W_in cvt) + 512 (W_out cvt) = 2624 blocks x 256.
__global__ __launch_bounds__(256) void prep_k(const float* __restrict__ x,
                                              const float* __restrict__ W_in,
                                              const float* __restrict__ W_out,
                                              const float* __restrict__ nw,
                                              const float* __restrict__ dtb,
                                              float* __restrict__ dtp,
                                              u16* __restrict__ xb16,
                                              u16* __restrict__ wint,
                                              u16* __restrict__ woutt) {
  __shared__ float shmem[8 * 1024];  // 32 KB (dt) / reused as tile[64][65] (cvt)
  const int t = threadIdx.x;
  const int bid = blockIdx.x;
  if (bid < 1024) {
    // dt = softplus(x @ W_in[:,4352:] + b), exact fp32; also emit x as bf16
    const int row0 = bid * 8;
#pragma unroll
    for (int i = 0; i < 8; ++i) {
      int j4 = i * 256 + t;
      float4 v = *(const float4*)&x[(size_t)row0 * DM + j4 * 4];
      *(float4*)&shmem[j4 * 4] = v;
      u32 lo = (u32)f2us(v.x) | ((u32)f2us(v.y) << 16);
      u32 hi = (u32)f2us(v.z) | ((u32)f2us(v.w) << 16);
      *(uint2*)&xb16[(size_t)row0 * DM + j4 * 4] = make_uint2(lo, hi);
    }
    __syncthreads();
    const int r = t >> 5, h = t & 31;
    float a0 = 0.f, a1 = 0.f, a2 = 0.f, a3 = 0.f;
    const float* wcol = W_in + (DI + CONVD) + h;
    const float* xr = &shmem[r * 1024];
    for (int k = 0; k < 1024; k += 4) {
      float4 xv = *(const float4*)&xr[k];
      a0 += xv.x * wcol[(size_t)(k + 0) * DPROJ];
      a1 += xv.y * wcol[(size_t)(k + 1) * DPROJ];
      a2 += xv.z * wcol[(size_t)(k + 2) * DPROJ];
      a3 += xv.w * wcol[(size_t)(k + 3) * DPROJ];
    }
    float v = (a0 + a1) + (a2 + a3) + dtb[h];
    dtp[(size_t)(row0 + r) * NH + h] = (v > 20.0f) ? v : log1pf(__expf(v));
  } else {
    float (*tile)[65] = (float(*)[65])shmem;
    const float* W; u16* Wt; int ldW, ldT, n0, k0; bool fold;
    if (bid < 2112) {  // W_in -> wint[n][k], bf16, no fold
      int j = bid - 1024;
      W = W_in; Wt = wint; ldW = DPROJ; ldT = DM; fold = false;
      n0 = (j % (NGEMM / 64)) * 64; k0 = (j / (NGEMM / 64)) * 64;
    } else {           // W_out*nw -> woutt[n][k], bf16
      int j = bid - 2112;
      W = W_out; Wt = woutt; ldW = DM; ldT = DI; fold = true;
      n0 = (j % (DM / 64)) * 64; k0 = (j / (DM / 64)) * 64;
    }
#pragma unroll
    for (int i = 0; i < 16; ++i) {
      int j = i * 256 + t;
      int kk = j >> 6, nn = j & 63;
      float v = W[(size_t)(k0 + kk) * ldW + n0 + nn];
      if (fold) v *= nw[k0 + kk];
      tile[kk][nn] = v;
    }
    __syncthreads();
#pragma unroll
    for (int i = 0; i < 16; ++i) {
      int j = i * 256 + t;
      int nn = j >> 6, kk = j & 63;
      Wt[(size_t)(n0 + nn) * ldT + k0 + kk] = f2us(tile[kk][nn]);
    }
  }
}

// ==== 256x128 bf16 MFMA GEMM (in-proj) ======================================
__global__ __launch_bounds__(512, 4) void gemm_in_k(const u16* __restrict__ A,
                                                    const u16* __restrict__ Bt,
                                                    u16* __restrict__ zb,
                                                    u16* __restrict__ xraw,
                                                    int nwg) {
  __shared__ u16 pool[24576];   // Al[256][64] @0, Bl[128][64] @16384
  u16* Al = pool;
  u16* Bl = pool + 16384;
  const int t = threadIdx.x;
  const int w = t >> 6, lane = t & 63;
  const int fr = lane & 15, oct = lane >> 4;
  const int wm = w >> 1, wn = w & 1;
  const int q = nwg >> 3;
  const int wg = (blockIdx.x & 7) * q + (blockIdx.x >> 3);
  const int bm = wg / (NGEMM / 128), bn = wg % (NGEMM / 128);
  const int m0 = bm * 256, n0 = bn * 128;
  const int lr = lane >> 3, ls = lane & 7;
  const int gslot = (ls ^ lr) * 8;   // XOR involution: LDS[r][s] = G[r][s^(r&7)]

  f32x4 acc[4][4];
#pragma unroll
  for (int mm = 0; mm < 4; ++mm)
#pragma unroll
    for (int nn = 0; nn < 4; ++nn) acc[mm][nn] = (f32x4){0.f, 0.f, 0.f, 0.f};

  for (int k0 = 0; k0 < DM; k0 += 64) {
    if (k0) __syncthreads();
#pragma unroll
    for (int i = 0; i < 4; ++i) {
      const int rowA = w * 32 + i * 8;
      gload16(&A[(size_t)(m0 + rowA + lr) * DM + k0 + gslot], &Al[rowA * 64]);
    }
#pragma unroll
    for (int i = 0; i < 2; ++i) {
      const int rowB = w * 16 + i * 8;
      gload16(&Bt[(size_t)(n0 + rowB + lr) * DM + k0 + gslot], &Bl[rowB * 64]);
    }
    __syncthreads();
#pragma unroll
    for (int kk = 0; kk < 2; ++kk) {
      bf16x8 af[4], bfr[4];
#pragma unroll
      for (int mm = 0; mm < 4; ++mm)
        af[mm] = *(const bf16x8*)&Al[(wm * 64 + mm * 16 + fr) * 64 +
                                     (((kk * 4 + oct) ^ (fr & 7)) * 8)];
#pragma unroll
      for (int nn = 0; nn < 4; ++nn)
        bfr[nn] = *(const bf16x8*)&Bl[(wn * 64 + nn * 16 + fr) * 64 +
                                      (((kk * 4 + oct) ^ (fr & 7)) * 8)];
      __builtin_amdgcn_s_setprio(1);
#pragma unroll
      for (int mm = 0; mm < 4; ++mm)
#pragma unroll
        for (int nn = 0; nn < 4; ++nn)
          acc[mm][nn] = __builtin_amdgcn_mfma_f32_16x16x32_bf16(af[mm], bfr[nn],
                                                                acc[mm][nn], 0, 0, 0);
      __builtin_amdgcn_s_setprio(0);
    }
  }

  const bool isz = (n0 < DI);
  u16* Oh = pool;
#pragma unroll
  for (int P = 0; P < 4; ++P) {
    __syncthreads();
    if (wm == P) {
#pragma unroll
      for (int mm = 0; mm < 4; ++mm)
#pragma unroll
        for (int i = 0; i < 4; ++i) {
          int rloc = mm * 16 + oct * 4 + i;
#pragma unroll
          for (int nn = 0; nn < 4; ++nn)
            Oh[rloc * 136 + wn * 64 + nn * 16 + fr] = f2us(acc[mm][nn][i]);
        }
    }
    __syncthreads();
#pragma unroll
    for (int p = 0; p < 2; ++p) {
      int e = p * 512 + t;
      int row = e >> 4, cs = (e & 15) * 8;
      uint4 v = *(const uint4*)&Oh[row * 136 + cs];
      size_t grow = m0 + P * 64 + row;
      int col = n0 + cs;
      if (isz) *(uint4*)&zb[grow * DI + col] = v;
      else     *(uint4*)&xraw[grow * CONVD + (col - DI)] = v;
    }
  }
}

// ---- bf16 MFMA GEMM 128x128 (out-proj): rowsum prologue + RMS epilogue ------
template <int KDIM, int NTN>
__global__ __launch_bounds__(256) void gemm_out_k(const u16* __restrict__ A,
                                                  const u16* __restrict__ Bt,
                                                  const float* __restrict__ psum,
                                                  float* __restrict__ outf,
                                                  int nwg) {
  __shared__ u16 pool[17408];
  __shared__ float rs_s[128];
  u16* Al = pool;
  u16* Bl = pool + 8192;
  const int t = threadIdx.x;
  const int wv = t >> 6, lane = t & 63;
  const int fr = lane & 15, oct = lane >> 4;
  const int wr = wv >> 1, wc = wv & 1;
  const int q = nwg >> 3;
  const int wg = (blockIdx.x & 7) * q + (blockIdx.x >> 3);
  const int bm = wg / NTN, bn = wg % NTN;
  const int m0 = bm * 128, n0 = bn * 128;

  // rowsum prologue: rs_s[r] = rsqrt(mean(v^2)+eps) for rows m0..m0+127
  if (t < 128) {
    const float4* p = (const float4*)&psum[(size_t)(m0 + t) * 32];
    float s = 0.0f;
#pragma unroll
    for (int i = 0; i < 8; ++i) {
      float4 v = p[i];
      s += (v.x + v.y) + (v.z + v.w);
    }
    rs_s[t] = rsqrtf(s * (1.0f / DI) + 1e-5f);
  }

  const int lr = lane >> 3, ls = lane & 7;
  const int gslot = (ls ^ lr) * 8;

  f32x4 acc[4][4];
#pragma unroll
  for (int mm = 0; mm < 4; ++mm)
#pragma unroll
    for (int nn = 0; nn < 4; ++nn) acc[mm][nn] = (f32x4){0.f, 0.f, 0.f, 0.f};

  for (int k0 = 0; k0 < KDIM; k0 += 64) {
    if (k0) __syncthreads();
#pragma unroll
    for (int i = 0; i < 4; ++i) {
      const int rowA = wv * 32 + i * 8;
      gload16(&A[(size_t)(m0 + rowA + lr) * KDIM + k0 + gslot], &Al[rowA * 64]);
      gload16(&Bt[(size_t)(n0 + rowA + lr) * KDIM + k0 + gslot], &Bl[rowA * 64]);
    }
    __syncthreads();
#pragma unroll
    for (int kk = 0; kk < 2; ++kk) {
      bf16x8 af[4], bfr[4];
#pragma unroll
      for (int mm = 0; mm < 4; ++mm)
        af[mm] = *(const bf16x8*)&Al[(wr * 64 + mm * 16 + fr) * 64 +
                                     (((kk * 4 + oct) ^ (fr & 7)) * 8)];
#pragma unroll
      for (int nn = 0; nn < 4; ++nn)
        bfr[nn] = *(const bf16x8*)&Bl[(wc * 64 + nn * 16 + fr) * 64 +
                                      (((kk * 4 + oct) ^ (fr & 7)) * 8)];
#pragma unroll
      for (int mm = 0; mm < 4; ++mm)
#pragma unroll
        for (int nn = 0; nn < 4; ++nn)
          acc[mm][nn] = __builtin_amdgcn_mfma_f32_16x16x32_bf16(af[mm], bfr[nn],
                                                                acc[mm][nn], 0, 0, 0);
    }
  }

#pragma unroll
  for (int P = 0; P < 2; ++P) {
    __syncthreads();
    float* Of = (float*)pool;  // [64][132]
    if (wr == P) {
#pragma unroll
      for (int mm = 0; mm < 4; ++mm)
#pragma unroll
        for (int i = 0; i < 4; ++i) {
          int rloc = mm * 16 + oct * 4 + i;
#pragma unroll
          for (int nn = 0; nn < 4; ++nn)
            Of[rloc * 132 + wc * 64 + nn * 16 + fr] = acc[mm][nn][i];
        }
    }
    __syncthreads();
#pragma unroll
    for (int p = 0; p < 8; ++p) {
      int e = p * 256 + t;
      int row = e >> 5, c4 = (e & 31) * 4;
      float s = rs_s[P * 64 + row];
      float4 v = *(const float4*)&Of[row * 132 + c4];
      v.x *= s; v.y *= s; v.z *= s; v.w *= s;
      *(float4*)&outf[(size_t)(m0 + P * 64 + row) * DM + n0 + c4] = v;
    }
  }
}

// ---- causal depthwise conv(4) + SiLU ----------------------------------------
__global__ __launch_bounds__(256) void conv_silu_k(const u16* __restrict__ xraw,
                                                   const float* __restrict__ cw,
                                                   const float* __restrict__ cb,
                                                   u16* __restrict__ xbc) {
  int idx = blockIdx.x * 256 + threadIdx.x;
  int ch8 = idx % (CONVD / 8);
  int bl = idx / (CONVD / 8);
  int l = bl & (L_ - 1);
  int ch = ch8 * 8;
  const u16* src = xraw + (size_t)bl * CONVD + ch;
  float a[8], o[8];
#pragma unroll
  for (int qq = 0; qq < 8; ++qq) a[qq] = cb[ch + qq];
  float w0[8], w1[8], w2[8], w3[8];
#pragma unroll
  for (int qq = 0; qq < 8; ++qq) {
    float4 w = *(const float4*)&cw[(ch + qq) * 4];
    w0[qq] = w.x; w1[qq] = w.y; w2[qq] = w.z; w3[qq] = w.w;
  }
  if (l >= 3) {
    uint4 v = *(const uint4*)&src[-3 * CONVD]; unpack8(v, o);
#pragma unroll
    for (int qq = 0; qq < 8; ++qq) a[qq] += o[qq] * w0[qq];
  }
  if (l >= 2) {
    uint4 v = *(const uint4*)&src[-2 * CONVD]; unpack8(v, o);
#pragma unroll
    for (int qq = 0; qq < 8; ++qq) a[qq] += o[qq] * w1[qq];
  }
  if (l >= 1) {
    uint4 v = *(const uint4*)&src[-CONVD]; unpack8(v, o);
#pragma unroll
    for (int qq = 0; qq < 8; ++qq) a[qq] += o[qq] * w2[qq];
  }
  {
    uint4 v = *(const uint4*)&src[0]; unpack8(v, o);
#pragma unroll
    for (int qq = 0; qq < 8; ++qq) a[qq] += o[qq] * w3[qq];
  }
  uint4 ov;
  ov.x = (u32)f2us(silu_(a[0])) | ((u32)f2us(silu_(a[1])) << 16);
  ov.y = (u32)f2us(silu_(a[2])) | ((u32)f2us(silu_(a[3])) << 16);
  ov.z = (u32)f2us(silu_(a[4])) | ((u32)f2us(silu_(a[5])) << 16);
  ov.w = (u32)f2us(silu_(a[6])) | ((u32)f2us(silu_(a[7])) << 16);
  *(uint4*)&xbc[(size_t)bl * CONVD + ch] = ov;
}

// ---- chunk end-states via MFMA -> bf16; computes+publishes Acs --------------
#define SLP 72
__global__ __launch_bounds__(256) void states_k(const u16* __restrict__ xbc,
                                                const float* __restrict__ dtp,
                                                const float* __restrict__ A_log,
                                                float* __restrict__ Acs,
                                                u16* __restrict__ st16) {
  __shared__ u16 BtT[128 * SLP];
  __shared__ u16 XtT[64 * SLP];
  __shared__ float acs_s[256];
  const int t = threadIdx.x;
  const int wv = t >> 6, lane = t & 63;
  const int fr = lane & 15, oct = lane >> 4;
  const int sw = (blockIdx.x & 7) * 128 + (blockIdx.x >> 3);  // XCD swizzle
  const int h = sw & 31, c = (sw >> 5) & 15, b = sw >> 9;
  const size_t acsb = (((size_t)b * NH + h) * NC + c) * CH;
  const size_t rowbase = (size_t)b * L_ + c * CH;

  // wave 0: cumsum of dt*A over this chunk -> LDS + global Acs
  if (t < 64) {
    const float Ah = -__expf(A_log[h]);
    const size_t base = (rowbase + t * 4) * NH + h;
    float v0 = dtp[base] * Ah;
    float v1 = dtp[base + NH] * Ah;
    float v2 = dtp[base + 2 * NH] * Ah;
    float v3 = dtp[base + 3 * NH] * Ah;
    float c1 = v0 + v1, c2 = c1 + v2, c3 = c2 + v3;
    float tot = c3;
#pragma unroll
    for (int off = 1; off < 64; off <<= 1) {
      float p = __shfl_up(tot, off, 64);
      if (t >= off) tot += p;
    }
    float excl = tot - c3;
    float4 ov = make_float4(excl + v0, excl + c1, excl + c2, excl + c3);
    *(float4*)&acs_s[t * 4] = ov;
    *(float4*)&Acs[acsb + t * 4] = ov;
  }
  __syncthreads();
  const float acs_last = acs_s[255];

  f32x4 acc[2][4];
#pragma unroll
  for (int mt = 0; mt < 2; ++mt)
#pragma unroll
    for (int pt = 0; pt < 4; ++pt) acc[mt][pt] = (f32x4){0.f, 0.f, 0.f, 0.f};

  for (int lt = 0; lt < 4; ++lt) {
    __syncthreads();
#pragma unroll
    for (int i = 0; i < 2; ++i) {
      int ci = i * 256 + t;
      int lp = ci >> 4, nk = ci & 15;
      int l0 = lp * 2;
      const u16* srcp = &xbc[(rowbase + lt * 64 + l0) * CONVD + DI + nk * 8];
      uint4 v0 = *(const uint4*)srcp;
      uint4 v1 = *(const uint4*)(srcp + CONVD);
      u16 a0[8], a1[8];
      unpk16(v0, a0); unpk16(v1, a1);
#pragma unroll
      for (int qq = 0; qq < 8; ++qq) {
        int r = nk * 8 + qq;
        u32 val = (u32)a0[qq] | ((u32)a1[qq] << 16);
        *(u32*)&BtT[r * SLP + ((((l0 >> 3) ^ (r >> 3)) & 7) << 3) + (l0 & 7)] = val;
      }
    }
    {
      int lp = t >> 3, pk = t & 7;
      int l0 = lp * 2;
      size_t row0 = rowbase + lt * 64 + l0;
      uint4 v0 = *(const uint4*)&xbc[row0 * CONVD + h * HD + pk * 8];
      uint4 v1 = *(const uint4*)&xbc[(row0 + 1) * CONVD + h * HD + pk * 8];
      float d0 = dtp[row0 * NH + h] * __expf(acs_last - acs_s[lt * 64 + l0]);
      float d1 = dtp[(row0 + 1) * NH + h] * __expf(acs_last - acs_s[lt * 64 + l0 + 1]);
      float o0[8], o1[8];
      unpack8(v0, o0); unpack8(v1, o1);
#pragma unroll
      for (int qq = 0; qq < 8; ++qq) {
        int r = pk * 8 + qq;
        u32 val = (u32)f2us(o0[qq] * d0) | ((u32)f2us(o1[qq] * d1) << 16);
        *(u32*)&XtT[r * SLP + ((((l0 >> 3) ^ (r >> 3)) & 7) << 3) + (l0 & 7)] = val;
      }
    }
    __syncthreads();
    __builtin_amdgcn_s_setprio(1);
#pragma unroll
    for (int ks = 0; ks < 2; ++ks) {
      bf16x8 afr[2], bfr[4];
#pragma unroll
      for (int mt = 0; mt < 2; ++mt) {
        int r = wv * 32 + mt * 16 + fr;
        afr[mt] = *(const bf16x8*)&BtT[r * SLP + ((((ks * 4 + oct) ^ (r >> 3)) & 7) << 3)];
      }
#pragma unroll
      for (int pt = 0; pt < 4; ++pt) {
        int r = pt * 16 + fr;
        bfr[pt] = *(const bf16x8*)&XtT[r * SLP + ((((ks * 4 + oct) ^ (r >> 3)) & 7) << 3)];
      }
#pragma unroll
      for (int mt = 0; mt < 2; ++mt)
#pragma unroll
        for (int pt = 0; pt < 4; ++pt)
          acc[mt][pt] = __builtin_amdgcn_mfma_f32_16x16x32_bf16(afr[mt], bfr[pt],
                                                                acc[mt][pt], 0, 0, 0);
    }
    __builtin_amdgcn_s_setprio(0);
  }
  size_t sbase = (((size_t)b * NC + c) * NH + h) * (size_t)(HD * DS);
#pragma unroll
  for (int mt = 0; mt < 2; ++mt)
#pragma unroll
    for (int pt = 0; pt < 4; ++pt) {
      int p = pt * 16 + fr;
      int n0 = wv * 32 + mt * 16 + oct * 4;
      u32 lo = (u32)f2us(acc[mt][pt][0]) | ((u32)f2us(acc[mt][pt][1]) << 16);
      u32 hi = (u32)f2us(acc[mt][pt][2]) | ((u32)f2us(acc[mt][pt][3]) << 16);
      *(uint2*)&st16[sbase + (size_t)p * DS + n0] = make_uint2(lo, hi);
    }
}

// ---- inter-chunk scan (bf16 states, fp32 carry) -----------------------------
__global__ __launch_bounds__(256) void scan_k(u16* __restrict__ st16,
                                              const float* __restrict__ Acs) {
  const int t = threadIdx.x;
  const int seg = blockIdx.x & 15;
  const int bh = blockIdx.x >> 4;
  const int h = bh & 31, b = bh >> 5;
  const int e2 = seg * 256 + t;
  const size_t acssb = ((size_t)b * NH + h) * NC * CH;
  float run0 = 0.0f, run1 = 0.0f;
#pragma unroll
  for (int c = 0; c < NC; ++c) {
    float dAl = __expf(Acs[acssb + (size_t)c * CH + (CH - 1)]);
    size_t e = (((size_t)b * NC + c) * NH + h) * (size_t)(HD * DS) + e2 * 2;
    u32 v = *(const u32*)&st16[e];
    float s0 = us2f((u16)(v & 0xffffu)), s1 = us2f((u16)(v >> 16));
    *(u32*)&st16[e] = (u32)f2us(run0) | ((u32)f2us(run1) << 16);
    run0 = fmaf(dAl, run0, s0);
    run1 = fmaf(dAl, run1, s1);
  }
}

// ---- merged SSD + gated-v + partial row-sums --------------------------------
#define SP 72
#define XOFF 8192
#define POFF 12800
__global__ __launch_bounds__(512, 4) void ssd_out_k(const u16* __restrict__ xbc,
                                                    const float* __restrict__ dtp,
                                                    const float* __restrict__ Acs,
                                                    const u16* __restrict__ st16,
                                                    const float* __restrict__ Dvec,
                                                    const u16* __restrict__ zb,
                                                    u16* __restrict__ v_out,
                                                    float* __restrict__ psum) {
  __shared__ u16 pool[31232];
  __shared__ float acs_s[256];
  const int t = threadIdx.x;
  const int w = t >> 6, lane = t & 63;
  const int fr = lane & 15, oct = lane >> 4;
  const int sw = (blockIdx.x & 7) * 128 + (blockIdx.x >> 3);  // XCD swizzle
  const int h = sw & 31, c = (sw >> 5) & 15, b = sw >> 9;
  const size_t acsb = (((size_t)b * NH + h) * NC + c) * CH;
  const size_t rowbase = (size_t)b * L_ + c * CH;
  if (t < 256) acs_s[t] = Acs[acsb + t];
  const size_t sb = (((size_t)b * NC + c) * NH + h) * (size_t)(HD * DS);
#pragma unroll
  for (int i = 0; i < 2; ++i) {
    int ci = i * 512 + t; int p = ci >> 4, nk = ci & 15;
    uint4 v = *(const uint4*)&st16[sb + (size_t)p * DS + nk * 8];
    *(uint4*)&pool[p * 136 + nk * 8] = v;
  }
  __syncthreads();
  bf16x8 ca[2][4];
#pragma unroll
  for (int mt = 0; mt < 2; ++mt)
#pragma unroll
    for (int kk = 0; kk < 4; ++kk)
      ca[mt][kk] = *(const bf16x8*)&xbc[(rowbase + w * 32 + mt * 16 + fr) * CONVD +
                                        DI + DS + kk * 32 + oct * 8];
  f32x4 acc_y[2][4];
#pragma unroll
  for (int mt = 0; mt < 2; ++mt)
#pragma unroll
    for (int pp4 = 0; pp4 < 4; ++pp4) acc_y[mt][pp4] = (f32x4){0.f, 0.f, 0.f, 0.f};

  {
    float eL0 = __expf(acs_s[w * 32 + fr]);
    float eL1 = __expf(acs_s[w * 32 + 16 + fr]);
    __builtin_amdgcn_s_setprio(1);
#pragma unroll
    for (int kk = 0; kk < 4; ++kk) {
      bf16x8 c0 = scale8(ca[0][kk], eL0);
      bf16x8 c1 = scale8(ca[1][kk], eL1);
#pragma unroll
      for (int pp4 = 0; pp4 < 4; ++pp4) {
        bf16x8 sf = *(const bf16x8*)&pool[(pp4 * 16 + fr) * 136 + kk * 32 + oct * 8];
        acc_y[0][pp4] = __builtin_amdgcn_mfma_f32_16x16x32_bf16(c0, sf, acc_y[0][pp4], 0, 0, 0);
        acc_y[1][pp4] = __builtin_amdgcn_mfma_f32_16x16x32_bf16(c1, sf, acc_y[1][pp4], 0, 0, 0);
      }
    }
    __builtin_amdgcn_s_setprio(0);
  }

  const int stmax = w >> 1, delta = (w & 1) << 5;
  for (int st = 0; st < 4; ++st) {
    __syncthreads();
#pragma unroll
    for (int i = 0; i < 2; ++i) {
      int ci = i * 512 + t; int ll = ci >> 4, ck = ci & 15;
      uint4 v = *(const uint4*)&xbc[(rowbase + st * 64 + ll) * CONVD + DI + ck * 8];
      *(uint4*)&pool[ll * 128 + ((ck * 8) ^ ((ll & 7) << 3))] = v;
    }
    if (t < 256) {
      int lp = t >> 3, pk = t & 7;
      int s0 = lp * 2;
      size_t row0 = rowbase + st * 64 + s0;
      uint4 v0 = *(const uint4*)&xbc[row0 * CONVD + h * HD + pk * 8];
      uint4 v1 = *(const uint4*)&xbc[(row0 + 1) * CONVD + h * HD + pk * 8];
      float d0 = dtp[row0 * NH + h];
      float d1 = dtp[(row0 + 1) * NH + h];
      float o0[8], o1[8];
      unpack8(v0, o0); unpack8(v1, o1);
#pragma unroll
      for (int qq = 0; qq < 8; ++qq) {
        int r = pk * 8 + qq;
        u32 val = (u32)f2us(o0[qq] * d0) | ((u32)f2us(o1[qq] * d1) << 16);
        *(u32*)&pool[XOFF + r * SP + ((((s0 >> 3) ^ (r >> 3)) & 7) << 3) + (s0 & 7)] = val;
      }
    }
    __syncthreads();
    if (st > stmax) continue;
    const bool diag = (st == stmax);
#pragma unroll
    for (int ss4 = 0; ss4 < 4; ++ss4) {
      bf16x8 bbf[4];
#pragma unroll
      for (int kk = 0; kk < 4; ++kk)
        bbf[kk] = *(const bf16x8*)&pool[(ss4 * 16 + fr) * 128 +
                                        ((kk * 32 + oct * 8) ^ ((fr & 7) << 3))];
      int s_in = ss4 * 16 + fr;
      float aS = acs_s[st * 64 + s_in];
#pragma unroll
      for (int mt = 0; mt < 2; ++mt) {
        f32x4 sacc = (f32x4){0.f, 0.f, 0.f, 0.f};
        __builtin_amdgcn_s_setprio(1);
#pragma unroll
        for (int kk = 0; kk < 4; ++kk)
          sacc = __builtin_amdgcn_mfma_f32_16x16x32_bf16(ca[mt][kk], bbf[kk], sacc, 0, 0, 0);
        __builtin_amdgcn_s_setprio(0);
#pragma unroll
        for (int i = 0; i < 4; ++i) {
          int r = mt * 16 + oct * 4 + i;
          float aL = acs_s[w * 32 + r];
          float wgt = (!diag || (s_in <= r + delta)) ? __expf(aL - aS) : 0.0f;
          pool[POFF + w * 2304 + r * SP + s_in] = f2us(sacc[i] * wgt);
        }
      }
    }
    bf16x8 pa[2][2];
#pragma unroll
    for (int mt = 0; mt < 2; ++mt)
#pragma unroll
      for (int k2 = 0; k2 < 2; ++k2)
        pa[mt][k2] = *(const bf16x8*)&pool[POFF + w * 2304 + (mt * 16 + fr) * SP +
                                           k2 * 32 + oct * 8];
    __builtin_amdgcn_s_setprio(1);
#pragma unroll
    for (int pp4 = 0; pp4 < 4; ++pp4) {
      int rx = pp4 * 16 + fr, xg = rx >> 3;
      bf16x8 xb0 = *(const bf16x8*)&pool[XOFF + rx * SP + (((oct) ^ xg) & 7) * 8];
      bf16x8 xb1 = *(const bf16x8*)&pool[XOFF + rx * SP + (((4 + oct) ^ xg) & 7) * 8];
#pragma unroll
      for (int mt = 0; mt < 2; ++mt) {
        acc_y[mt][pp4] = __builtin_amdgcn_mfma_f32_16x16x32_bf16(pa[mt][0], xb0, acc_y[mt][pp4], 0, 0, 0);
        acc_y[mt][pp4] = __builtin_amdgcn_mfma_f32_16x16x32_bf16(pa[mt][1], xb1, acc_y[mt][pp4], 0, 0, 0);
      }
    }
    __builtin_amdgcn_s_setprio(0);
  }

  // epilogue: v = (Yd + Yo + D*xs) * silu(z); partial row-sums of v^2
  const float Dh = Dvec[h];
  float rs[2][4];
#pragma unroll
  for (int mt = 0; mt < 2; ++mt)
#pragma unroll
    for (int i = 0; i < 4; ++i) {
      size_t row = rowbase + w * 32 + mt * 16 + oct * 4 + i;
      float rsum = 0.0f;
#pragma unroll
      for (int pp4 = 0; pp4 < 4; ++pp4) {
        int col = h * HD + pp4 * 16 + fr;
        float xs = us2f(xbc[row * CONVD + col]);
        float zz = us2f(zb[row * DI + col]);
        float vv = (acc_y[mt][pp4][i] + Dh * xs) * silu_(zz);
        v_out[row * DI + col] = f2us(vv);
        rsum += vv * vv;
      }
      rs[mt][i] = rsum;
    }
#pragma unroll
  for (int mt = 0; mt < 2; ++mt)
#pragma unroll
    for (int i = 0; i < 4; ++i) {
      float s = rs[mt][i];
#pragma unroll
      for (int off = 8; off >= 1; off >>= 1) s += __shfl_xor(s, off, 64);
      if (fr == 0) {
        size_t row = rowbase + w * 32 + mt * 16 + oct * 4 + i;
        psum[row * 32 + h] = s;
      }
    }
}

extern "C" void kernel_launch(void* const* d_in, const int* in_sizes, int n_in,
                              void* d_out, int out_size, void* d_ws, size_t ws_size,
                              hipStream_t stream) {
  const float* x      = (const float*)d_in[0];
  const float* W_in   = (const float*)d_in[1];
  const float* conv_w = (const float*)d_in[2];
  const float* conv_b = (const float*)d_in[3];
  const float* dt_b   = (const float*)d_in[4];
  const float* A_log  = (const float*)d_in[5];
  const float* Dvec   = (const float*)d_in[6];
  const float* norm_w = (const float*)d_in[7];
  const float* W_out  = (const float*)d_in[8];
  float* out = (float*)d_out;

  u16* zb       = (u16*)d_ws;                              // 33.55 MB
  u16* xbc      = zb + (size_t)B_ * L_ * DI;               // 37.75 MB
  float* dtp    = (float*)(xbc + (size_t)B_ * L_ * CONVD); // 1.05 MB
  float* Acs    = dtp + (size_t)B_ * L_ * NH;              // 1.05 MB
  u16* stregion = (u16*)(Acs + (size_t)B_ * NH * L_);      // 33.55 MB region
  u16* uni      = stregion + (size_t)B_ * NC * NH * HD * DS * 2;  // 37.75 MB
  u16* xraw = uni;
  u16* v    = uni;   // v = gated SSD output, aliases xraw

  // stregion: xb16@0 | wint@16.78M | woutt@25.69M | psum@29.88M ; states16@0
  u16* xb16     = stregion;
  u16* wint     = stregion + (size_t)B_ * L_ * DM;
  u16* woutt    = wint + (size_t)NGEMM * DM;
  float* psum   = (float*)(woutt + (size_t)DM * DI);
  u16* states16 = stregion;   // reuses xb16/wint space after gemm_in

  const int Mrows = B_ * L_;

  prep_k<<<1024 + (NGEMM / 64) * (DM / 64) + (DM / 64) * (DI / 64), 256, 0, stream>>>(
      x, W_in, W_out, norm_w, dt_b, dtp, xb16, wint, woutt);

  const int nwg_in = (Mrows / 256) * (NGEMM / 128);   // 1088
  gemm_in_k<<<nwg_in, 512, 0, stream>>>(xb16, wint, zb, xraw, nwg_in);

  conv_silu_k<<<(Mrows * (CONVD / 8)) / 256, 256, 0, stream>>>(xraw, conv_w, conv_b, xbc);
  states_k<<<B_ * NC * NH, 256, 0, stream>>>(xbc, dtp, A_log, Acs, states16);
  scan_k<<<B_ * NH * 16, 256, 0, stream>>>(states16, Acs);
  ssd_out_k<<<B_ * NC * NH, 512, 0, stream>>>(xbc, dtp, Acs, states16, Dvec,
                                              zb, v, psum);

  const int nwg_out = (Mrows / 128) * (DM / 128);     // 512
  gemm_out_k<DI, DM / 128><<<nwg_out, 256, 0, stream>>>(v, woutt, psum, out, nwg_out);
}